// Round 2
// baseline (554.830 us; speedup 1.0000x reference)
//
#include <hip/hip_runtime.h>
#include <math.h>

#define Bq 2
#define Hq 128
#define Wq 256
#define Cq 64
#define HIDq 256
#define HWq (Hq * Wq)
#define NTOK (Bq * HWq)

#define TOKA 64
#define TOKB 64
#define TOKC 32
#define PIXD 16

__device__ inline float wave_reduce_sum(float v) {
    #pragma unroll
    for (int m = 1; m < 64; m <<= 1) v += __shfl_xor(v, m, 64);
    return v;
}

__device__ inline float gelu_exact(float x) {
    return 0.5f * x * (1.0f + erff(x * 0.70710678118654752440f));
}

// ============ Kernel A: LN1 + fused {Wv | Woff | Wa} GEMM, softmax, loc ======
__global__ __launch_bounds__(256) void kA(
    const float* __restrict__ x, const float* __restrict__ ref,
    const float* __restrict__ g1, const float* __restrict__ be1,
    const float* __restrict__ Woff, const float* __restrict__ boff,
    const float* __restrict__ Wa, const float* __restrict__ ba,
    const float* __restrict__ Wv, const float* __restrict__ bv,
    float* __restrict__ v_ws, float* __restrict__ loc_ws, float* __restrict__ attn_ws)
{
    __shared__ float Wc[64][128];      // cols: 0..63 Wv, 64..99 Woff, 100..117 Wa
    __shared__ float hsb[TOKA][68];
    __shared__ float outs[TOKA][56];   // off(36) + attn logits(18)
    const int t = threadIdx.x;
    const int tok0 = blockIdx.x * TOKA;
    const int b = tok0 >> 15;          // HW = 32768
    const int pix0 = tok0 & (HWq - 1);

    // stage fused weight matrix
    for (int idx = t; idx < 64 * 128; idx += 256) {
        const int j = idx >> 7, c = idx & 127;
        float w = 0.0f;
        if (c < 64) w = Wv[j * 64 + c];
        else if (c < 100) w = Woff[j * 36 + (c - 64)];
        else if (c < 118) w = Wa[j * 18 + (c - 100)];
        Wc[j][c] = w;
    }

    // LayerNorm: wave wv handles 16 tokens, lane = channel
    const int lane = t & 63, wvid = t >> 6;
    const float gv = g1[lane], bev = be1[lane];
    for (int i = 0; i < 16; ++i) {
        const int tk = wvid * 16 + i;
        float xv = x[(size_t)(tok0 + tk) * 64 + lane];
        float m = wave_reduce_sum(xv) * (1.0f / 64.0f);
        float d = xv - m;
        float var = wave_reduce_sum(d * d) * (1.0f / 64.0f);
        hsb[tk][lane] = d * rsqrtf(var + 1e-5f) * gv + bev;
    }
    __syncthreads();

    // GEMM phase: 4 tok x 8 col register tile
    const int cg = t & 15, tg = t >> 4;
    const int cbase = cg * 8;
    const int tb = tg * 4;
    float acc[4][8];
    #pragma unroll
    for (int i = 0; i < 4; ++i)
        #pragma unroll
        for (int q = 0; q < 8; ++q) acc[i][q] = 0.0f;

    for (int j = 0; j < 64; j += 4) {
        const float4 h0 = *(const float4*)&hsb[tb + 0][j];
        const float4 h1 = *(const float4*)&hsb[tb + 1][j];
        const float4 h2 = *(const float4*)&hsb[tb + 2][j];
        const float4 h3 = *(const float4*)&hsb[tb + 3][j];
        const float hv[4][4] = {{h0.x,h0.y,h0.z,h0.w},{h1.x,h1.y,h1.z,h1.w},
                                {h2.x,h2.y,h2.z,h2.w},{h3.x,h3.y,h3.z,h3.w}};
        #pragma unroll
        for (int jj = 0; jj < 4; ++jj) {
            const float4 wA = *(const float4*)&Wc[j + jj][cbase];
            const float4 wB = *(const float4*)&Wc[j + jj][cbase + 4];
            const float wv8[8] = {wA.x,wA.y,wA.z,wA.w,wB.x,wB.y,wB.z,wB.w};
            #pragma unroll
            for (int i = 0; i < 4; ++i)
                #pragma unroll
                for (int q = 0; q < 8; ++q)
                    acc[i][q] = fmaf(hv[i][jj], wv8[q], acc[i][q]);
        }
    }

    // epilogue: v -> global (channel-last image), off/attn -> LDS
    if (cbase < 64) {
        const int n = cbase >> 5, cc = cbase & 31;
        float bv8[8];
        #pragma unroll
        for (int q = 0; q < 8; ++q) bv8[q] = bv[cbase + q];
        #pragma unroll
        for (int i = 0; i < 4; ++i) {
            const int pix = pix0 + tb + i;
            float* dst = &v_ws[((size_t)(b * 2 + n) * HWq + pix) * 32 + cc];
            float4 s0 = {acc[i][0]+bv8[0], acc[i][1]+bv8[1], acc[i][2]+bv8[2], acc[i][3]+bv8[3]};
            float4 s1 = {acc[i][4]+bv8[4], acc[i][5]+bv8[5], acc[i][6]+bv8[6], acc[i][7]+bv8[7]};
            *(float4*)dst = s0;
            *(float4*)(dst + 4) = s1;
        }
    } else {
        #pragma unroll
        for (int q = 0; q < 8; ++q) {
            const int c = cbase + q;
            float bias = 0.0f;
            bool valid = true;
            if (c < 100) bias = boff[c - 64];
            else if (c < 118) bias = ba[c - 100];
            else valid = false;
            if (valid) {
                #pragma unroll
                for (int i = 0; i < 4; ++i) outs[tb + i][c - 64] = acc[i][q] + bias;
            }
        }
    }
    __syncthreads();

    // loc = ref + off
    for (int idx = t; idx < TOKA * 36; idx += 256) {
        const int tk = idx / 36, co = idx - tk * 36;
        const int tokg = tok0 + tk;
        loc_ws[(size_t)tokg * 36 + co] = ref[(size_t)tokg * 18 + (co % 18)] + outs[tk][co];
    }
    // softmax per (token, head)
    if (t < TOKA * 2) {
        const int tk = t >> 1, head = t & 1;
        const int base = 36 + head * 9;
        float mx = -1e30f;
        #pragma unroll
        for (int k = 0; k < 9; ++k) mx = fmaxf(mx, outs[tk][base + k]);
        float e[9], s = 0.0f;
        #pragma unroll
        for (int k = 0; k < 9; ++k) { e[k] = expf(outs[tk][base + k] - mx); s += e[k]; }
        const float inv = 1.0f / s;
        float* dst = &attn_ws[(size_t)(tok0 + tk) * 18 + head * 9];
        #pragma unroll
        for (int k = 0; k < 9; ++k) dst[k] = e[k] * inv;
    }
}

// ============ Kernel B: bilinear sample + attn + Wo + residual ===============
__global__ __launch_bounds__(256) void kB(
    const float* __restrict__ x, const float* __restrict__ v_ws,
    const float* __restrict__ loc_ws, const float* __restrict__ attn_ws,
    const float* __restrict__ Wo, const float* __restrict__ bo,
    float* __restrict__ out)
{
    __shared__ float Wo_s[64][64];
    __shared__ float sout[TOKB][68];
    __shared__ float loc_s[TOKB][36];
    __shared__ float attn_s[TOKB][18];
    const int t = threadIdx.x;
    const int tok0 = blockIdx.x * TOKB;
    const int b = tok0 >> 15;

    for (int i4 = t; i4 < 64 * 64 / 4; i4 += 256)
        ((float4*)Wo_s)[i4] = ((const float4*)Wo)[i4];
    for (int i4 = t; i4 < TOKB * 36 / 4; i4 += 256)
        ((float4*)loc_s)[i4] = ((const float4*)(loc_ws + (size_t)tok0 * 36))[i4];
    for (int i4 = t; i4 < TOKB * 18 / 4; i4 += 256)
        ((float4*)attn_s)[i4] = ((const float4*)(attn_ws + (size_t)tok0 * 18))[i4];
    __syncthreads();

    // sampling: wave handles 16 tokens, lane = channel
    const int lane = t & 63, wvid = t >> 6;
    const int n = lane >> 5, cc = lane & 31;
    const float* __restrict__ vimg = v_ws + (size_t)(b * 2 + n) * HWq * 32;
    for (int i = 0; i < 16; ++i) {
        const int tk = wvid * 16 + i;
        float accs = 0.0f;
        #pragma unroll
        for (int k = 0; k < 9; ++k) {
            const float gx = loc_s[tk][n * 18 + k * 2 + 0];
            const float gy = loc_s[tk][n * 18 + k * 2 + 1];
            const float a  = attn_s[tk][n * 9 + k];
            const float ix = (gx + 1.0f) * 128.0f - 0.5f;
            const float iy = (gy + 1.0f) * 64.0f - 0.5f;
            const float x0f = floorf(ix), y0f = floorf(iy);
            const float wx1 = ix - x0f, wy1 = iy - y0f;
            const int x0 = (int)x0f, y0 = (int)y0f;
            float s = 0.0f;
            if (x0 >= 0 && x0 < Wq && y0 >= 0 && y0 < Hq)
                s += (1.0f - wx1) * (1.0f - wy1) * vimg[((size_t)y0 * Wq + x0) * 32 + cc];
            if (x0 + 1 >= 0 && x0 + 1 < Wq && y0 >= 0 && y0 < Hq)
                s += wx1 * (1.0f - wy1) * vimg[((size_t)y0 * Wq + (x0 + 1)) * 32 + cc];
            if (x0 >= 0 && x0 < Wq && y0 + 1 >= 0 && y0 + 1 < Hq)
                s += (1.0f - wx1) * wy1 * vimg[((size_t)(y0 + 1) * Wq + x0) * 32 + cc];
            if (x0 + 1 >= 0 && x0 + 1 < Wq && y0 + 1 >= 0 && y0 + 1 < Hq)
                s += wx1 * wy1 * vimg[((size_t)(y0 + 1) * Wq + (x0 + 1)) * 32 + cc];
            accs = fmaf(a, s, accs);
        }
        sout[tk][lane] = accs;
    }
    __syncthreads();

    // Wo GEMM: 4 tok x 4 col tile
    const int cg = t & 15, tg = t >> 4;
    const int cb = cg * 4, tb = tg * 4;
    float acc[4][4];
    #pragma unroll
    for (int i = 0; i < 4; ++i)
        #pragma unroll
        for (int q = 0; q < 4; ++q) acc[i][q] = 0.0f;

    for (int j = 0; j < 64; j += 4) {
        const float4 h0 = *(const float4*)&sout[tb + 0][j];
        const float4 h1 = *(const float4*)&sout[tb + 1][j];
        const float4 h2 = *(const float4*)&sout[tb + 2][j];
        const float4 h3 = *(const float4*)&sout[tb + 3][j];
        const float hv[4][4] = {{h0.x,h0.y,h0.z,h0.w},{h1.x,h1.y,h1.z,h1.w},
                                {h2.x,h2.y,h2.z,h2.w},{h3.x,h3.y,h3.z,h3.w}};
        #pragma unroll
        for (int jj = 0; jj < 4; ++jj) {
            const float4 w = *(const float4*)&Wo_s[j + jj][cb];
            const float wv4[4] = {w.x, w.y, w.z, w.w};
            #pragma unroll
            for (int i = 0; i < 4; ++i)
                #pragma unroll
                for (int q = 0; q < 4; ++q)
                    acc[i][q] = fmaf(hv[i][jj], wv4[q], acc[i][q]);
        }
    }
    const float4 bo4 = *(const float4*)&bo[cb];
    #pragma unroll
    for (int i = 0; i < 4; ++i) {
        const size_t tokg = tok0 + tb + i;
        const float4 r = *(const float4*)&x[tokg * 64 + cb];
        float4 o = {acc[i][0]+bo4.x+r.x, acc[i][1]+bo4.y+r.y,
                    acc[i][2]+bo4.z+r.z, acc[i][3]+bo4.w+r.w};
        *(float4*)&out[tokg * 64 + cb] = o;
    }
}

// ============ Kernel C: LN2 + W1 + GELU ======================================
__global__ __launch_bounds__(256) void kC(
    const float* __restrict__ x1, const float* __restrict__ g2, const float* __restrict__ be2,
    const float* __restrict__ W1, const float* __restrict__ c1,
    float* __restrict__ y_ws)
{
    __shared__ float W1s[64][256];
    __shared__ float hs2[TOKC][68];
    const int t = threadIdx.x;
    const int tok0 = blockIdx.x * TOKC;

    for (int i4 = t; i4 < 64 * 256 / 4; i4 += 256)
        ((float4*)W1s)[i4] = ((const float4*)W1)[i4];

    const int lane = t & 63, wvid = t >> 6;
    const float gv = g2[lane], bev = be2[lane];
    for (int i = 0; i < TOKC / 4; ++i) {
        const int tk = wvid * (TOKC / 4) + i;
        float xv = x1[(size_t)(tok0 + tk) * 64 + lane];
        float m = wave_reduce_sum(xv) * (1.0f / 64.0f);
        float d = xv - m;
        float var = wave_reduce_sum(d * d) * (1.0f / 64.0f);
        hs2[tk][lane] = d * rsqrtf(var + 1e-5f) * gv + bev;
    }
    __syncthreads();

    // GEMM: 4 tok x 8 hid tile (32 tok x 256 hid per block)
    const int cg = t & 31, tg = t >> 5;
    const int hb = cg * 8, tb = tg * 4;
    float acc[4][8];
    #pragma unroll
    for (int i = 0; i < 4; ++i)
        #pragma unroll
        for (int q = 0; q < 8; ++q) acc[i][q] = 0.0f;

    for (int j = 0; j < 64; j += 4) {
        const float4 h0 = *(const float4*)&hs2[tb + 0][j];
        const float4 h1 = *(const float4*)&hs2[tb + 1][j];
        const float4 h2 = *(const float4*)&hs2[tb + 2][j];
        const float4 h3 = *(const float4*)&hs2[tb + 3][j];
        const float hv[4][4] = {{h0.x,h0.y,h0.z,h0.w},{h1.x,h1.y,h1.z,h1.w},
                                {h2.x,h2.y,h2.z,h2.w},{h3.x,h3.y,h3.z,h3.w}};
        #pragma unroll
        for (int jj = 0; jj < 4; ++jj) {
            const float4 wA = *(const float4*)&W1s[j + jj][hb];
            const float4 wB = *(const float4*)&W1s[j + jj][hb + 4];
            const float wv8[8] = {wA.x,wA.y,wA.z,wA.w,wB.x,wB.y,wB.z,wB.w};
            #pragma unroll
            for (int i = 0; i < 4; ++i)
                #pragma unroll
                for (int q = 0; q < 8; ++q)
                    acc[i][q] = fmaf(hv[i][jj], wv8[q], acc[i][q]);
        }
    }
    float c18[8];
    #pragma unroll
    for (int q = 0; q < 8; ++q) c18[q] = c1[hb + q];
    #pragma unroll
    for (int i = 0; i < 4; ++i) {
        const size_t tokg = tok0 + tb + i;
        float r[8];
        #pragma unroll
        for (int q = 0; q < 8; ++q) r[q] = gelu_exact(acc[i][q] + c18[q]);
        float4 s0 = {r[0], r[1], r[2], r[3]};
        float4 s1 = {r[4], r[5], r[6], r[7]};
        float* dst = &y_ws[tokg * 256 + hb];
        *(float4*)dst = s0;
        *(float4*)(dst + 4) = s1;
    }
}

// ============ Kernel D: depthwise 3x3 + GELU + W2 + residual =================
__global__ __launch_bounds__(256) void kD(
    const float* __restrict__ y_ws, const float* __restrict__ Wdw, const float* __restrict__ bdw,
    const float* __restrict__ W2, const float* __restrict__ c2,
    float* __restrict__ out)
{
    __shared__ float W2s[256][64];
    __shared__ float zsb[PIXD][256];
    const int t = threadIdx.x;
    const int bid = blockIdx.x;                 // 2 * 128 * 16 = 4096 blocks
    const int b = bid >> 11;                    // 2048 per batch
    const int rem = bid & 2047;
    const int hh = rem >> 4;                    // 16 strips per row
    const int ww0 = (rem & 15) * PIXD;

    for (int i4 = t; i4 < 256 * 64 / 4; i4 += 256)
        ((float4*)W2s)[i4] = ((const float4*)W2)[i4];

    // phase 1: depthwise conv, thread = channel, slide over PIXD pixels
    {
        const float* __restrict__ yb = y_ws + (size_t)b * HWq * 256;
        float wd[9];
        #pragma unroll
        for (int q = 0; q < 9; ++q) wd[q] = Wdw[t * 9 + q];
        const float bdv = bdw[t];
        const bool r0ok = (hh > 0), r2ok = (hh < Hq - 1);
        const int y0r = (hh - 1) << 8, y1r = hh << 8, y2r = (hh + 1) << 8;

        float u0[3], u1[3], u2[3];
        {
            const int xm = (ww0 - 1) & 255, xc = ww0;
            u0[0] = r0ok ? yb[(size_t)(y0r + xm) * 256 + t] : 0.0f;
            u0[1] =        yb[(size_t)(y1r + xm) * 256 + t];
            u0[2] = r2ok ? yb[(size_t)(y2r + xm) * 256 + t] : 0.0f;
            u1[0] = r0ok ? yb[(size_t)(y0r + xc) * 256 + t] : 0.0f;
            u1[1] =        yb[(size_t)(y1r + xc) * 256 + t];
            u1[2] = r2ok ? yb[(size_t)(y2r + xc) * 256 + t] : 0.0f;
        }
        #pragma unroll 4
        for (int p = 0; p < PIXD; ++p) {
            const int xp = (ww0 + p + 1) & 255;
            u2[0] = r0ok ? yb[(size_t)(y0r + xp) * 256 + t] : 0.0f;
            u2[1] =        yb[(size_t)(y1r + xp) * 256 + t];
            u2[2] = r2ok ? yb[(size_t)(y2r + xp) * 256 + t] : 0.0f;
            float a = bdv;
            a = fmaf(wd[0], u0[0], a); a = fmaf(wd[1], u1[0], a); a = fmaf(wd[2], u2[0], a);
            a = fmaf(wd[3], u0[1], a); a = fmaf(wd[4], u1[1], a); a = fmaf(wd[5], u2[1], a);
            a = fmaf(wd[6], u0[2], a); a = fmaf(wd[7], u1[2], a); a = fmaf(wd[8], u2[2], a);
            zsb[p][t] = gelu_exact(a);
            u0[0] = u1[0]; u0[1] = u1[1]; u0[2] = u1[2];
            u1[0] = u2[0]; u1[1] = u2[1]; u1[2] = u2[2];
        }
    }
    __syncthreads();

    // phase 2: z @ W2 + c2 + residual. Wave handles 4 pixels, lane = out channel.
    const int lane = t & 63, wvid = t >> 6;
    const int pb = wvid * 4;
    float acc[4] = {0.0f, 0.0f, 0.0f, 0.0f};
    #pragma unroll 2
    for (int j = 0; j < 256; j += 4) {
        const float w0 = W2s[j + 0][lane];
        const float w1 = W2s[j + 1][lane];
        const float w2 = W2s[j + 2][lane];
        const float w3 = W2s[j + 3][lane];
        #pragma unroll
        for (int i = 0; i < 4; ++i) {
            const float4 z = *(const float4*)&zsb[pb + i][j];
            acc[i] = fmaf(z.x, w0, acc[i]);
            acc[i] = fmaf(z.y, w1, acc[i]);
            acc[i] = fmaf(z.z, w2, acc[i]);
            acc[i] = fmaf(z.w, w3, acc[i]);
        }
    }
    const float c2v = c2[lane];
    #pragma unroll
    for (int i = 0; i < 4; ++i) {
        const size_t tokg = (size_t)b * HWq + ((size_t)hh << 8) + ww0 + pb + i;
        out[tokg * 64 + lane] += acc[i] + c2v;
    }
}

extern "C" void kernel_launch(void* const* d_in, const int* in_sizes, int n_in,
                              void* d_out, int out_size, void* d_ws, size_t ws_size,
                              hipStream_t stream) {
    const float* x    = (const float*)d_in[0];
    const float* ref  = (const float*)d_in[1];
    const float* g1   = (const float*)d_in[2];
    const float* be1  = (const float*)d_in[3];
    const float* g2   = (const float*)d_in[4];
    const float* be2  = (const float*)d_in[5];
    const float* Woff = (const float*)d_in[6];
    const float* boff = (const float*)d_in[7];
    const float* Wa   = (const float*)d_in[8];
    const float* ba   = (const float*)d_in[9];
    const float* Wv   = (const float*)d_in[10];
    const float* bv   = (const float*)d_in[11];
    const float* Wo   = (const float*)d_in[12];
    const float* bo   = (const float*)d_in[13];
    const float* W1   = (const float*)d_in[14];
    const float* c1   = (const float*)d_in[15];
    const float* Wdw  = (const float*)d_in[16];
    const float* bdw  = (const float*)d_in[17];
    const float* W2   = (const float*)d_in[18];
    const float* c2   = (const float*)d_in[19];

    float* out = (float*)d_out;
    float* ws = (float*)d_ws;
    float* v_ws    = ws;                                   // B*2*HW*32
    float* loc_ws  = v_ws  + (size_t)Bq * 2 * HWq * 32;    // NTOK*36
    float* attn_ws = loc_ws + (size_t)NTOK * 36;           // NTOK*18
    float* y_ws    = attn_ws + (size_t)NTOK * 18;          // NTOK*256

    hipLaunchKernelGGL(kA, dim3(NTOK / TOKA), dim3(256), 0, stream,
                       x, ref, g1, be1, Woff, boff, Wa, ba, Wv, bv,
                       v_ws, loc_ws, attn_ws);
    hipLaunchKernelGGL(kB, dim3(NTOK / TOKB), dim3(256), 0, stream,
                       x, v_ws, loc_ws, attn_ws, Wo, bo, out);
    hipLaunchKernelGGL(kC, dim3(NTOK / TOKC), dim3(256), 0, stream,
                       out, g2, be2, W1, c1, y_ws);
    hipLaunchKernelGGL(kD, dim3(Bq * Hq * (Wq / PIXD)), dim3(256), 0, stream,
                       y_ws, Wdw, bdw, W2, c2, out);
}

// Round 3
// 297.872 us; speedup vs baseline: 1.8626x; 1.8626x over previous
//
#include <hip/hip_runtime.h>
#include <math.h>

#define Bq 2
#define Hq 128
#define Wq 256
#define Cq 64
#define HIDq 256
#define HWq (Hq * Wq)
#define NTOK (Bq * HWq)

#define TOKA 64
#define TOKB 32
#define TOKC 32
#define PIXD 16

__device__ inline float wave_reduce_sum(float v) {
    #pragma unroll
    for (int m = 1; m < 64; m <<= 1) v += __shfl_xor(v, m, 64);
    return v;
}

__device__ inline float gelu_exact(float x) {
    return 0.5f * x * (1.0f + erff(x * 0.70710678118654752440f));
}

// ============ Kernel A: LN1 + fused {Wv | Woff | Wa} GEMM, softmax, loc ======
__global__ __launch_bounds__(256) void kA(
    const float* __restrict__ x, const float* __restrict__ ref,
    const float* __restrict__ g1, const float* __restrict__ be1,
    const float* __restrict__ Woff, const float* __restrict__ boff,
    const float* __restrict__ Wa, const float* __restrict__ ba,
    const float* __restrict__ Wv, const float* __restrict__ bv,
    float* __restrict__ v_ws, float* __restrict__ loc_ws, float* __restrict__ attn_ws)
{
    __shared__ float Wc[64][128];      // cols: 0..63 Wv, 64..99 Woff, 100..117 Wa
    __shared__ float hsb[TOKA][68];
    __shared__ float outs[TOKA][56];   // off(36) + attn logits(18)
    const int t = threadIdx.x;
    const int tok0 = blockIdx.x * TOKA;
    const int b = tok0 >> 15;          // HW = 32768
    const int pix0 = tok0 & (HWq - 1);

    // stage fused weight matrix
    for (int idx = t; idx < 64 * 128; idx += 256) {
        const int j = idx >> 7, c = idx & 127;
        float w = 0.0f;
        if (c < 64) w = Wv[j * 64 + c];
        else if (c < 100) w = Woff[j * 36 + (c - 64)];
        else if (c < 118) w = Wa[j * 18 + (c - 100)];
        Wc[j][c] = w;
    }

    // LayerNorm: wave wv handles 16 tokens, lane = channel
    const int lane = t & 63, wvid = t >> 6;
    const float gv = g1[lane], bev = be1[lane];
    for (int i = 0; i < 16; ++i) {
        const int tk = wvid * 16 + i;
        float xv = x[(size_t)(tok0 + tk) * 64 + lane];
        float m = wave_reduce_sum(xv) * (1.0f / 64.0f);
        float d = xv - m;
        float var = wave_reduce_sum(d * d) * (1.0f / 64.0f);
        hsb[tk][lane] = d * rsqrtf(var + 1e-5f) * gv + bev;
    }
    __syncthreads();

    // GEMM phase: 4 tok x 8 col register tile
    const int cg = t & 15, tg = t >> 4;
    const int cbase = cg * 8;
    const int tb = tg * 4;
    float acc[4][8];
    #pragma unroll
    for (int i = 0; i < 4; ++i)
        #pragma unroll
        for (int q = 0; q < 8; ++q) acc[i][q] = 0.0f;

    for (int j = 0; j < 64; j += 4) {
        const float4 h0 = *(const float4*)&hsb[tb + 0][j];
        const float4 h1 = *(const float4*)&hsb[tb + 1][j];
        const float4 h2 = *(const float4*)&hsb[tb + 2][j];
        const float4 h3 = *(const float4*)&hsb[tb + 3][j];
        const float hv[4][4] = {{h0.x,h0.y,h0.z,h0.w},{h1.x,h1.y,h1.z,h1.w},
                                {h2.x,h2.y,h2.z,h2.w},{h3.x,h3.y,h3.z,h3.w}};
        #pragma unroll
        for (int jj = 0; jj < 4; ++jj) {
            const float4 wA = *(const float4*)&Wc[j + jj][cbase];
            const float4 wB = *(const float4*)&Wc[j + jj][cbase + 4];
            const float wv8[8] = {wA.x,wA.y,wA.z,wA.w,wB.x,wB.y,wB.z,wB.w};
            #pragma unroll
            for (int i = 0; i < 4; ++i)
                #pragma unroll
                for (int q = 0; q < 8; ++q)
                    acc[i][q] = fmaf(hv[i][jj], wv8[q], acc[i][q]);
        }
    }

    // epilogue: v -> global (channel-last image), off/attn -> LDS
    if (cbase < 64) {
        const int n = cbase >> 5, cc = cbase & 31;
        float bv8[8];
        #pragma unroll
        for (int q = 0; q < 8; ++q) bv8[q] = bv[cbase + q];
        #pragma unroll
        for (int i = 0; i < 4; ++i) {
            const int pix = pix0 + tb + i;
            float* dst = &v_ws[((size_t)(b * 2 + n) * HWq + pix) * 32 + cc];
            float4 s0 = {acc[i][0]+bv8[0], acc[i][1]+bv8[1], acc[i][2]+bv8[2], acc[i][3]+bv8[3]};
            float4 s1 = {acc[i][4]+bv8[4], acc[i][5]+bv8[5], acc[i][6]+bv8[6], acc[i][7]+bv8[7]};
            *(float4*)dst = s0;
            *(float4*)(dst + 4) = s1;
        }
    } else {
        #pragma unroll
        for (int q = 0; q < 8; ++q) {
            const int c = cbase + q;
            float bias = 0.0f;
            bool valid = true;
            if (c < 100) bias = boff[c - 64];
            else if (c < 118) bias = ba[c - 100];
            else valid = false;
            if (valid) {
                #pragma unroll
                for (int i = 0; i < 4; ++i) outs[tb + i][c - 64] = acc[i][q] + bias;
            }
        }
    }
    __syncthreads();

    // loc = ref + off
    for (int idx = t; idx < TOKA * 36; idx += 256) {
        const int tk = idx / 36, co = idx - tk * 36;
        const int tokg = tok0 + tk;
        loc_ws[(size_t)tokg * 36 + co] = ref[(size_t)tokg * 18 + (co % 18)] + outs[tk][co];
    }
    // softmax per (token, head)
    if (t < TOKA * 2) {
        const int tk = t >> 1, head = t & 1;
        const int base = 36 + head * 9;
        float mx = -1e30f;
        #pragma unroll
        for (int k = 0; k < 9; ++k) mx = fmaxf(mx, outs[tk][base + k]);
        float e[9], s = 0.0f;
        #pragma unroll
        for (int k = 0; k < 9; ++k) { e[k] = expf(outs[tk][base + k] - mx); s += e[k]; }
        const float inv = 1.0f / s;
        float* dst = &attn_ws[(size_t)(tok0 + tk) * 18 + head * 9];
        #pragma unroll
        for (int k = 0; k < 9; ++k) dst[k] = e[k] * inv;
    }
}

// ============ Kernel B: bilinear sample + attn + Wo + residual ===============
__global__ __launch_bounds__(256) void kB(
    const float* __restrict__ x, const float* __restrict__ v_ws,
    const float* __restrict__ loc_ws, const float* __restrict__ attn_ws,
    const float* __restrict__ Wo, const float* __restrict__ bo,
    float* __restrict__ out)
{
    __shared__ float sout[TOKB][68];
    __shared__ float loc_s[TOKB][36];
    __shared__ float attn_s[TOKB][18];
    const int t = threadIdx.x;
    // XCD-chunked swizzle: 2048 blocks, 8 XCDs, 256 contiguous blocks per XCD
    const int bid = (blockIdx.x & 7) * (NTOK / TOKB / 8) + (blockIdx.x >> 3);
    const int tok0 = bid * TOKB;
    const int b = tok0 >> 15;

    for (int i4 = t; i4 < TOKB * 36 / 4; i4 += 256)
        ((float4*)loc_s)[i4] = ((const float4*)(loc_ws + (size_t)tok0 * 36))[i4];
    for (int i4 = t; i4 < TOKB * 18 / 4; i4 += 256)
        ((float4*)attn_s)[i4] = ((const float4*)(attn_ws + (size_t)tok0 * 18))[i4];
    __syncthreads();

    // sampling: wave handles 8 tokens, lane = channel (n, cc)
    const int lane = t & 63, wvid = t >> 6;
    const int n = lane >> 5, cc = lane & 31;
    const float* __restrict__ vimg = v_ws + (size_t)(b * 2 + n) * HWq * 32;
    #pragma unroll 2
    for (int i = 0; i < 8; ++i) {
        const int tk = wvid * 8 + i;
        float accs = 0.0f;
        #pragma unroll
        for (int k = 0; k < 9; ++k) {
            const float gx = loc_s[tk][n * 18 + k * 2 + 0];
            const float gy = loc_s[tk][n * 18 + k * 2 + 1];
            const float a  = attn_s[tk][n * 9 + k];
            const float ix = fmaf(gx, 128.0f, 127.5f);   // (gx+1)*128 - 0.5
            const float iy = fmaf(gy, 64.0f, 63.5f);     // (gy+1)*64 - 0.5
            const float x0f = floorf(ix), y0f = floorf(iy);
            const float wx1 = ix - x0f, wy1 = iy - y0f;
            const float wx0 = 1.0f - wx1, wy0 = 1.0f - wy1;
            const int x0 = (int)x0f, y0 = (int)y0f;
            const int x1i = x0 + 1, y1i = y0 + 1;
            const int x0c = min(max(x0, 0), Wq - 1), y0c = min(max(y0, 0), Hq - 1);
            const int x1c = min(max(x1i, 0), Wq - 1), y1c = min(max(y1i, 0), Hq - 1);
            const bool vx0 = (x0 >= 0) & (x0 <= Wq - 1);
            const bool vy0 = (y0 >= 0) & (y0 <= Hq - 1);
            const bool vx1 = (x1i >= 0) & (x1i <= Wq - 1);
            const bool vy1 = (y1i >= 0) & (y1i <= Hq - 1);
            // 4 independent, unconditional (clamped) gathers
            const float v00 = vimg[(((y0c << 8) + x0c) << 5) + cc];
            const float v10 = vimg[(((y0c << 8) + x1c) << 5) + cc];
            const float v01 = vimg[(((y1c << 8) + x0c) << 5) + cc];
            const float v11 = vimg[(((y1c << 8) + x1c) << 5) + cc];
            float s = 0.0f;
            s = fmaf((vx0 && vy0) ? wx0 * wy0 : 0.0f, v00, s);
            s = fmaf((vx1 && vy0) ? wx1 * wy0 : 0.0f, v10, s);
            s = fmaf((vx0 && vy1) ? wx0 * wy1 : 0.0f, v01, s);
            s = fmaf((vx1 && vy1) ? wx1 * wy1 : 0.0f, v11, s);
            accs = fmaf(a, s, accs);
        }
        sout[tk][lane] = accs;
    }
    __syncthreads();

    // Wo GEMM: 2 tok x 4 col tile, Wo streamed through L1 (16 KB, broadcast)
    const int cg = t & 15, tg = t >> 4;
    const int cb = cg * 4, tb = tg * 2;
    float acc[2][4];
    #pragma unroll
    for (int i = 0; i < 2; ++i)
        #pragma unroll
        for (int q = 0; q < 4; ++q) acc[i][q] = 0.0f;

    for (int j = 0; j < 64; j += 4) {
        const float4 h0 = *(const float4*)&sout[tb + 0][j];
        const float4 h1 = *(const float4*)&sout[tb + 1][j];
        const float hv[2][4] = {{h0.x,h0.y,h0.z,h0.w},{h1.x,h1.y,h1.z,h1.w}};
        #pragma unroll
        for (int jj = 0; jj < 4; ++jj) {
            const float4 w = *(const float4*)&Wo[(size_t)(j + jj) * 64 + cb];
            const float wv4[4] = {w.x, w.y, w.z, w.w};
            #pragma unroll
            for (int i = 0; i < 2; ++i)
                #pragma unroll
                for (int q = 0; q < 4; ++q)
                    acc[i][q] = fmaf(hv[i][jj], wv4[q], acc[i][q]);
        }
    }
    const float4 bo4 = *(const float4*)&bo[cb];
    #pragma unroll
    for (int i = 0; i < 2; ++i) {
        const size_t tokg = (size_t)tok0 + tb + i;
        const float4 r = *(const float4*)&x[tokg * 64 + cb];
        float4 o = {acc[i][0]+bo4.x+r.x, acc[i][1]+bo4.y+r.y,
                    acc[i][2]+bo4.z+r.z, acc[i][3]+bo4.w+r.w};
        *(float4*)&out[tokg * 64 + cb] = o;
    }
}

// ============ Kernel C: LN2 + W1 + GELU ======================================
__global__ __launch_bounds__(256) void kC(
    const float* __restrict__ x1, const float* __restrict__ g2, const float* __restrict__ be2,
    const float* __restrict__ W1, const float* __restrict__ c1,
    float* __restrict__ y_ws)
{
    __shared__ float W1s[64][256];
    __shared__ float hs2[TOKC][68];
    const int t = threadIdx.x;
    const int tok0 = blockIdx.x * TOKC;

    for (int i4 = t; i4 < 64 * 256 / 4; i4 += 256)
        ((float4*)W1s)[i4] = ((const float4*)W1)[i4];

    const int lane = t & 63, wvid = t >> 6;
    const float gv = g2[lane], bev = be2[lane];
    for (int i = 0; i < TOKC / 4; ++i) {
        const int tk = wvid * (TOKC / 4) + i;
        float xv = x1[(size_t)(tok0 + tk) * 64 + lane];
        float m = wave_reduce_sum(xv) * (1.0f / 64.0f);
        float d = xv - m;
        float var = wave_reduce_sum(d * d) * (1.0f / 64.0f);
        hs2[tk][lane] = d * rsqrtf(var + 1e-5f) * gv + bev;
    }
    __syncthreads();

    // GEMM: 4 tok x 8 hid tile (32 tok x 256 hid per block)
    const int cg = t & 31, tg = t >> 5;
    const int hb = cg * 8, tb = tg * 4;
    float acc[4][8];
    #pragma unroll
    for (int i = 0; i < 4; ++i)
        #pragma unroll
        for (int q = 0; q < 8; ++q) acc[i][q] = 0.0f;

    for (int j = 0; j < 64; j += 4) {
        const float4 h0 = *(const float4*)&hs2[tb + 0][j];
        const float4 h1 = *(const float4*)&hs2[tb + 1][j];
        const float4 h2 = *(const float4*)&hs2[tb + 2][j];
        const float4 h3 = *(const float4*)&hs2[tb + 3][j];
        const float hv[4][4] = {{h0.x,h0.y,h0.z,h0.w},{h1.x,h1.y,h1.z,h1.w},
                                {h2.x,h2.y,h2.z,h2.w},{h3.x,h3.y,h3.z,h3.w}};
        #pragma unroll
        for (int jj = 0; jj < 4; ++jj) {
            const float4 wA = *(const float4*)&W1s[j + jj][hb];
            const float4 wB = *(const float4*)&W1s[j + jj][hb + 4];
            const float wv8[8] = {wA.x,wA.y,wA.z,wA.w,wB.x,wB.y,wB.z,wB.w};
            #pragma unroll
            for (int i = 0; i < 4; ++i)
                #pragma unroll
                for (int q = 0; q < 8; ++q)
                    acc[i][q] = fmaf(hv[i][jj], wv8[q], acc[i][q]);
        }
    }
    float c18[8];
    #pragma unroll
    for (int q = 0; q < 8; ++q) c18[q] = c1[hb + q];
    #pragma unroll
    for (int i = 0; i < 4; ++i) {
        const size_t tokg = tok0 + tb + i;
        float r[8];
        #pragma unroll
        for (int q = 0; q < 8; ++q) r[q] = gelu_exact(acc[i][q] + c18[q]);
        float4 s0 = {r[0], r[1], r[2], r[3]};
        float4 s1 = {r[4], r[5], r[6], r[7]};
        float* dst = &y_ws[tokg * 256 + hb];
        *(float4*)dst = s0;
        *(float4*)(dst + 4) = s1;
    }
}

// ============ Kernel D: depthwise 3x3 + GELU + W2 + residual =================
__global__ __launch_bounds__(256) void kD(
    const float* __restrict__ y_ws, const float* __restrict__ Wdw, const float* __restrict__ bdw,
    const float* __restrict__ W2, const float* __restrict__ c2,
    float* __restrict__ out)
{
    __shared__ float W2s[256][64];
    __shared__ float zsb[PIXD][256];
    const int t = threadIdx.x;
    const int bid = blockIdx.x;                 // 2 * 128 * 16 = 4096 blocks
    const int b = bid >> 11;                    // 2048 per batch
    const int rem = bid & 2047;
    const int hh = rem >> 4;                    // 16 strips per row
    const int ww0 = (rem & 15) * PIXD;

    for (int i4 = t; i4 < 256 * 64 / 4; i4 += 256)
        ((float4*)W2s)[i4] = ((const float4*)W2)[i4];

    // phase 1: depthwise conv, thread = channel, slide over PIXD pixels
    {
        const float* __restrict__ yb = y_ws + (size_t)b * HWq * 256;
        float wd[9];
        #pragma unroll
        for (int q = 0; q < 9; ++q) wd[q] = Wdw[t * 9 + q];
        const float bdv = bdw[t];
        const bool r0ok = (hh > 0), r2ok = (hh < Hq - 1);
        const int y0r = (hh - 1) << 8, y1r = hh << 8, y2r = (hh + 1) << 8;

        float u0[3], u1[3], u2[3];
        {
            const int xm = (ww0 - 1) & 255, xc = ww0;
            u0[0] = r0ok ? yb[(size_t)(y0r + xm) * 256 + t] : 0.0f;
            u0[1] =        yb[(size_t)(y1r + xm) * 256 + t];
            u0[2] = r2ok ? yb[(size_t)(y2r + xm) * 256 + t] : 0.0f;
            u1[0] = r0ok ? yb[(size_t)(y0r + xc) * 256 + t] : 0.0f;
            u1[1] =        yb[(size_t)(y1r + xc) * 256 + t];
            u1[2] = r2ok ? yb[(size_t)(y2r + xc) * 256 + t] : 0.0f;
        }
        #pragma unroll 4
        for (int p = 0; p < PIXD; ++p) {
            const int xp = (ww0 + p + 1) & 255;
            u2[0] = r0ok ? yb[(size_t)(y0r + xp) * 256 + t] : 0.0f;
            u2[1] =        yb[(size_t)(y1r + xp) * 256 + t];
            u2[2] = r2ok ? yb[(size_t)(y2r + xp) * 256 + t] : 0.0f;
            float a = bdv;
            a = fmaf(wd[0], u0[0], a); a = fmaf(wd[1], u1[0], a); a = fmaf(wd[2], u2[0], a);
            a = fmaf(wd[3], u0[1], a); a = fmaf(wd[4], u1[1], a); a = fmaf(wd[5], u2[1], a);
            a = fmaf(wd[6], u0[2], a); a = fmaf(wd[7], u1[2], a); a = fmaf(wd[8], u2[2], a);
            zsb[p][t] = gelu_exact(a);
            u0[0] = u1[0]; u0[1] = u1[1]; u0[2] = u1[2];
            u1[0] = u2[0]; u1[1] = u2[1]; u1[2] = u2[2];
        }
    }
    __syncthreads();

    // phase 2: z @ W2 + c2 + residual. Wave handles 4 pixels, lane = out channel.
    const int lane = t & 63, wvid = t >> 6;
    const int pb = wvid * 4;
    float acc[4] = {0.0f, 0.0f, 0.0f, 0.0f};
    #pragma unroll 2
    for (int j = 0; j < 256; j += 4) {
        const float w0 = W2s[j + 0][lane];
        const float w1 = W2s[j + 1][lane];
        const float w2 = W2s[j + 2][lane];
        const float w3 = W2s[j + 3][lane];
        #pragma unroll
        for (int i = 0; i < 4; ++i) {
            const float4 z = *(const float4*)&zsb[pb + i][j];
            acc[i] = fmaf(z.x, w0, acc[i]);
            acc[i] = fmaf(z.y, w1, acc[i]);
            acc[i] = fmaf(z.z, w2, acc[i]);
            acc[i] = fmaf(z.w, w3, acc[i]);
        }
    }
    const float c2v = c2[lane];
    #pragma unroll
    for (int i = 0; i < 4; ++i) {
        const size_t tokg = (size_t)b * HWq + ((size_t)hh << 8) + ww0 + pb + i;
        out[tokg * 64 + lane] += acc[i] + c2v;
    }
}

extern "C" void kernel_launch(void* const* d_in, const int* in_sizes, int n_in,
                              void* d_out, int out_size, void* d_ws, size_t ws_size,
                              hipStream_t stream) {
    const float* x    = (const float*)d_in[0];
    const float* ref  = (const float*)d_in[1];
    const float* g1   = (const float*)d_in[2];
    const float* be1  = (const float*)d_in[3];
    const float* g2   = (const float*)d_in[4];
    const float* be2  = (const float*)d_in[5];
    const float* Woff = (const float*)d_in[6];
    const float* boff = (const float*)d_in[7];
    const float* Wa   = (const float*)d_in[8];
    const float* ba   = (const float*)d_in[9];
    const float* Wv   = (const float*)d_in[10];
    const float* bv   = (const float*)d_in[11];
    const float* Wo   = (const float*)d_in[12];
    const float* bo   = (const float*)d_in[13];
    const float* W1   = (const float*)d_in[14];
    const float* c1   = (const float*)d_in[15];
    const float* Wdw  = (const float*)d_in[16];
    const float* bdw  = (const float*)d_in[17];
    const float* W2   = (const float*)d_in[18];
    const float* c2   = (const float*)d_in[19];

    float* out = (float*)d_out;
    float* ws = (float*)d_ws;
    float* v_ws    = ws;                                   // B*2*HW*32
    float* loc_ws  = v_ws  + (size_t)Bq * 2 * HWq * 32;    // NTOK*36
    float* attn_ws = loc_ws + (size_t)NTOK * 36;           // NTOK*18
    float* y_ws    = attn_ws + (size_t)NTOK * 18;          // NTOK*256

    hipLaunchKernelGGL(kA, dim3(NTOK / TOKA), dim3(256), 0, stream,
                       x, ref, g1, be1, Woff, boff, Wa, ba, Wv, bv,
                       v_ws, loc_ws, attn_ws);
    hipLaunchKernelGGL(kB, dim3(NTOK / TOKB), dim3(256), 0, stream,
                       x, v_ws, loc_ws, attn_ws, Wo, bo, out);
    hipLaunchKernelGGL(kC, dim3(NTOK / TOKC), dim3(256), 0, stream,
                       out, g2, be2, W1, c1, y_ws);
    hipLaunchKernelGGL(kD, dim3(Bq * Hq * (Wq / PIXD)), dim3(256), 0, stream,
                       y_ws, Wdw, bdw, W2, c2, out);
}

// Round 4
// 213.268 us; speedup vs baseline: 2.6016x; 1.3967x over previous
//
#include <hip/hip_runtime.h>
#include <math.h>

#define Bq 2
#define Hq 128
#define Wq 256
#define Cq 64
#define HIDq 256
#define HWq (Hq * Wq)
#define NTOK (Bq * HWq)

#define TOKA 64
#define TOKB 32
#define TOKC 32
#define PIXD 16

typedef __attribute__((ext_vector_type(8))) short short8v;
typedef __attribute__((ext_vector_type(4))) float f32x4v;

__device__ inline float wave_reduce_sum(float v) {
    #pragma unroll
    for (int m = 1; m < 64; m <<= 1) v += __shfl_xor(v, m, 64);
    return v;
}

__device__ inline float gelu_exact(float x) {
    return 0.5f * x * (1.0f + erff(x * 0.70710678118654752440f));
}

__device__ inline unsigned short f2bf(float f) {
    unsigned int u = __float_as_uint(f);
    u += 0x7FFFu + ((u >> 16) & 1u);
    return (unsigned short)(u >> 16);
}

// ============ Kernel A: LN1 + fused {Wv | Woff | Wa} GEMM, softmax, loc ======
__global__ __launch_bounds__(256) void kA(
    const float* __restrict__ x, const float* __restrict__ ref,
    const float* __restrict__ g1, const float* __restrict__ be1,
    const float* __restrict__ Woff, const float* __restrict__ boff,
    const float* __restrict__ Wa, const float* __restrict__ ba,
    const float* __restrict__ Wv, const float* __restrict__ bv,
    float* __restrict__ v_ws, float* __restrict__ loc_ws, float* __restrict__ attn_ws)
{
    __shared__ float Wc[64][128];      // cols: 0..63 Wv, 64..99 Woff, 100..117 Wa
    __shared__ float hsb[TOKA][68];
    __shared__ float outs[TOKA][56];   // off(36) + attn logits(18)
    const int t = threadIdx.x;
    const int tok0 = blockIdx.x * TOKA;
    const int b = tok0 >> 15;          // HW = 32768
    const int pix0 = tok0 & (HWq - 1);

    // stage fused weight matrix
    for (int idx = t; idx < 64 * 128; idx += 256) {
        const int j = idx >> 7, c = idx & 127;
        float w = 0.0f;
        if (c < 64) w = Wv[j * 64 + c];
        else if (c < 100) w = Woff[j * 36 + (c - 64)];
        else if (c < 118) w = Wa[j * 18 + (c - 100)];
        Wc[j][c] = w;
    }

    // LayerNorm: wave wv handles 16 tokens, lane = channel
    const int lane = t & 63, wvid = t >> 6;
    const float gv = g1[lane], bev = be1[lane];
    for (int i = 0; i < 16; ++i) {
        const int tk = wvid * 16 + i;
        float xv = x[(size_t)(tok0 + tk) * 64 + lane];
        float m = wave_reduce_sum(xv) * (1.0f / 64.0f);
        float d = xv - m;
        float var = wave_reduce_sum(d * d) * (1.0f / 64.0f);
        hsb[tk][lane] = d * rsqrtf(var + 1e-5f) * gv + bev;
    }
    __syncthreads();

    // GEMM phase: 4 tok x 8 col register tile
    const int cg = t & 15, tg = t >> 4;
    const int cbase = cg * 8;
    const int tb = tg * 4;
    float acc[4][8];
    #pragma unroll
    for (int i = 0; i < 4; ++i)
        #pragma unroll
        for (int q = 0; q < 8; ++q) acc[i][q] = 0.0f;

    for (int j = 0; j < 64; j += 4) {
        const float4 h0 = *(const float4*)&hsb[tb + 0][j];
        const float4 h1 = *(const float4*)&hsb[tb + 1][j];
        const float4 h2 = *(const float4*)&hsb[tb + 2][j];
        const float4 h3 = *(const float4*)&hsb[tb + 3][j];
        const float hv[4][4] = {{h0.x,h0.y,h0.z,h0.w},{h1.x,h1.y,h1.z,h1.w},
                                {h2.x,h2.y,h2.z,h2.w},{h3.x,h3.y,h3.z,h3.w}};
        #pragma unroll
        for (int jj = 0; jj < 4; ++jj) {
            const float4 wA = *(const float4*)&Wc[j + jj][cbase];
            const float4 wB = *(const float4*)&Wc[j + jj][cbase + 4];
            const float wv8[8] = {wA.x,wA.y,wA.z,wA.w,wB.x,wB.y,wB.z,wB.w};
            #pragma unroll
            for (int i = 0; i < 4; ++i)
                #pragma unroll
                for (int q = 0; q < 8; ++q)
                    acc[i][q] = fmaf(hv[i][jj], wv8[q], acc[i][q]);
        }
    }

    // epilogue: v -> global (channel-last image), off/attn -> LDS
    if (cbase < 64) {
        const int n = cbase >> 5, cc = cbase & 31;
        float bv8[8];
        #pragma unroll
        for (int q = 0; q < 8; ++q) bv8[q] = bv[cbase + q];
        #pragma unroll
        for (int i = 0; i < 4; ++i) {
            const int pix = pix0 + tb + i;
            float* dst = &v_ws[((size_t)(b * 2 + n) * HWq + pix) * 32 + cc];
            float4 s0 = {acc[i][0]+bv8[0], acc[i][1]+bv8[1], acc[i][2]+bv8[2], acc[i][3]+bv8[3]};
            float4 s1 = {acc[i][4]+bv8[4], acc[i][5]+bv8[5], acc[i][6]+bv8[6], acc[i][7]+bv8[7]};
            *(float4*)dst = s0;
            *(float4*)(dst + 4) = s1;
        }
    } else {
        #pragma unroll
        for (int q = 0; q < 8; ++q) {
            const int c = cbase + q;
            float bias = 0.0f;
            bool valid = true;
            if (c < 100) bias = boff[c - 64];
            else if (c < 118) bias = ba[c - 100];
            else valid = false;
            if (valid) {
                #pragma unroll
                for (int i = 0; i < 4; ++i) outs[tb + i][c - 64] = acc[i][q] + bias;
            }
        }
    }
    __syncthreads();

    // loc = ref + off
    for (int idx = t; idx < TOKA * 36; idx += 256) {
        const int tk = idx / 36, co = idx - tk * 36;
        const int tokg = tok0 + tk;
        loc_ws[(size_t)tokg * 36 + co] = ref[(size_t)tokg * 18 + (co % 18)] + outs[tk][co];
    }
    // softmax per (token, head)
    if (t < TOKA * 2) {
        const int tk = t >> 1, head = t & 1;
        const int base = 36 + head * 9;
        float mx = -1e30f;
        #pragma unroll
        for (int k = 0; k < 9; ++k) mx = fmaxf(mx, outs[tk][base + k]);
        float e[9], s = 0.0f;
        #pragma unroll
        for (int k = 0; k < 9; ++k) { e[k] = expf(outs[tk][base + k] - mx); s += e[k]; }
        const float inv = 1.0f / s;
        float* dst = &attn_ws[(size_t)(tok0 + tk) * 18 + head * 9];
        #pragma unroll
        for (int k = 0; k < 9; ++k) dst[k] = e[k] * inv;
    }
}

// ============ Kernel B: bilinear sample + attn + Wo + residual ===============
__global__ __launch_bounds__(256) void kB(
    const float* __restrict__ x, const float* __restrict__ v_ws,
    const float* __restrict__ loc_ws, const float* __restrict__ attn_ws,
    const float* __restrict__ Wo, const float* __restrict__ bo,
    float* __restrict__ out)
{
    __shared__ float sout[TOKB][68];
    __shared__ float loc_s[TOKB][36];
    __shared__ float attn_s[TOKB][18];
    const int t = threadIdx.x;
    // XCD-chunked swizzle: 2048 blocks, 8 XCDs, 256 contiguous blocks per XCD
    const int bid = (blockIdx.x & 7) * (NTOK / TOKB / 8) + (blockIdx.x >> 3);
    const int tok0 = bid * TOKB;
    const int b = tok0 >> 15;

    for (int i4 = t; i4 < TOKB * 36 / 4; i4 += 256)
        ((float4*)loc_s)[i4] = ((const float4*)(loc_ws + (size_t)tok0 * 36))[i4];
    for (int i4 = t; i4 < TOKB * 18 / 4; i4 += 256)
        ((float4*)attn_s)[i4] = ((const float4*)(attn_ws + (size_t)tok0 * 18))[i4];
    __syncthreads();

    // sampling: wave handles 8 tokens, lane = channel (n, cc)
    const int lane = t & 63, wvid = t >> 6;
    const int n = lane >> 5, cc = lane & 31;
    const float* __restrict__ vimg = v_ws + (size_t)(b * 2 + n) * HWq * 32;
    #pragma unroll 2
    for (int i = 0; i < 8; ++i) {
        const int tk = wvid * 8 + i;
        float accs = 0.0f;
        #pragma unroll
        for (int k = 0; k < 9; ++k) {
            const float gx = loc_s[tk][n * 18 + k * 2 + 0];
            const float gy = loc_s[tk][n * 18 + k * 2 + 1];
            const float a  = attn_s[tk][n * 9 + k];
            const float ix = fmaf(gx, 128.0f, 127.5f);   // (gx+1)*128 - 0.5
            const float iy = fmaf(gy, 64.0f, 63.5f);     // (gy+1)*64 - 0.5
            const float x0f = floorf(ix), y0f = floorf(iy);
            const float wx1 = ix - x0f, wy1 = iy - y0f;
            const float wx0 = 1.0f - wx1, wy0 = 1.0f - wy1;
            const int x0 = (int)x0f, y0 = (int)y0f;
            const int x1i = x0 + 1, y1i = y0 + 1;
            const int x0c = min(max(x0, 0), Wq - 1), y0c = min(max(y0, 0), Hq - 1);
            const int x1c = min(max(x1i, 0), Wq - 1), y1c = min(max(y1i, 0), Hq - 1);
            const bool vx0 = (x0 >= 0) & (x0 <= Wq - 1);
            const bool vy0 = (y0 >= 0) & (y0 <= Hq - 1);
            const bool vx1 = (x1i >= 0) & (x1i <= Wq - 1);
            const bool vy1 = (y1i >= 0) & (y1i <= Hq - 1);
            // 4 independent, unconditional (clamped) gathers
            const float v00 = vimg[(((y0c << 8) + x0c) << 5) + cc];
            const float v10 = vimg[(((y0c << 8) + x1c) << 5) + cc];
            const float v01 = vimg[(((y1c << 8) + x0c) << 5) + cc];
            const float v11 = vimg[(((y1c << 8) + x1c) << 5) + cc];
            float s = 0.0f;
            s = fmaf((vx0 && vy0) ? wx0 * wy0 : 0.0f, v00, s);
            s = fmaf((vx1 && vy0) ? wx1 * wy0 : 0.0f, v10, s);
            s = fmaf((vx0 && vy1) ? wx0 * wy1 : 0.0f, v01, s);
            s = fmaf((vx1 && vy1) ? wx1 * wy1 : 0.0f, v11, s);
            accs = fmaf(a, s, accs);
        }
        sout[tk][lane] = accs;
    }
    __syncthreads();

    // Wo GEMM: 2 tok x 4 col tile, Wo streamed through L1 (16 KB, broadcast)
    const int cg = t & 15, tg = t >> 4;
    const int cb = cg * 4, tb = tg * 2;
    float acc[2][4];
    #pragma unroll
    for (int i = 0; i < 2; ++i)
        #pragma unroll
        for (int q = 0; q < 4; ++q) acc[i][q] = 0.0f;

    for (int j = 0; j < 64; j += 4) {
        const float4 h0 = *(const float4*)&sout[tb + 0][j];
        const float4 h1 = *(const float4*)&sout[tb + 1][j];
        const float hv[2][4] = {{h0.x,h0.y,h0.z,h0.w},{h1.x,h1.y,h1.z,h1.w}};
        #pragma unroll
        for (int jj = 0; jj < 4; ++jj) {
            const float4 w = *(const float4*)&Wo[(size_t)(j + jj) * 64 + cb];
            const float wv4[4] = {w.x, w.y, w.z, w.w};
            #pragma unroll
            for (int i = 0; i < 2; ++i)
                #pragma unroll
                for (int q = 0; q < 4; ++q)
                    acc[i][q] = fmaf(hv[i][jj], wv4[q], acc[i][q]);
        }
    }
    const float4 bo4 = *(const float4*)&bo[cb];
    #pragma unroll
    for (int i = 0; i < 2; ++i) {
        const size_t tokg = (size_t)tok0 + tb + i;
        const float4 r = *(const float4*)&x[tokg * 64 + cb];
        float4 o = {acc[i][0]+bo4.x+r.x, acc[i][1]+bo4.y+r.y,
                    acc[i][2]+bo4.z+r.z, acc[i][3]+bo4.w+r.w};
        *(float4*)&out[tokg * 64 + cb] = o;
    }
}

// ============ Kernel C: LN2 + W1 + GELU ======================================
__global__ __launch_bounds__(256) void kC(
    const float* __restrict__ x1, const float* __restrict__ g2, const float* __restrict__ be2,
    const float* __restrict__ W1, const float* __restrict__ c1,
    float* __restrict__ y_ws)
{
    __shared__ float W1s[64][256];
    __shared__ float hs2[TOKC][68];
    const int t = threadIdx.x;
    const int tok0 = blockIdx.x * TOKC;

    for (int i4 = t; i4 < 64 * 256 / 4; i4 += 256)
        ((float4*)W1s)[i4] = ((const float4*)W1)[i4];

    const int lane = t & 63, wvid = t >> 6;
    const float gv = g2[lane], bev = be2[lane];
    for (int i = 0; i < TOKC / 4; ++i) {
        const int tk = wvid * (TOKC / 4) + i;
        float xv = x1[(size_t)(tok0 + tk) * 64 + lane];
        float m = wave_reduce_sum(xv) * (1.0f / 64.0f);
        float d = xv - m;
        float var = wave_reduce_sum(d * d) * (1.0f / 64.0f);
        hs2[tk][lane] = d * rsqrtf(var + 1e-5f) * gv + bev;
    }
    __syncthreads();

    // GEMM: 4 tok x 8 hid tile (32 tok x 256 hid per block)
    const int cg = t & 31, tg = t >> 5;
    const int hb = cg * 8, tb = tg * 4;
    float acc[4][8];
    #pragma unroll
    for (int i = 0; i < 4; ++i)
        #pragma unroll
        for (int q = 0; q < 8; ++q) acc[i][q] = 0.0f;

    for (int j = 0; j < 64; j += 4) {
        const float4 h0 = *(const float4*)&hs2[tb + 0][j];
        const float4 h1 = *(const float4*)&hs2[tb + 1][j];
        const float4 h2 = *(const float4*)&hs2[tb + 2][j];
        const float4 h3 = *(const float4*)&hs2[tb + 3][j];
        const float hv[4][4] = {{h0.x,h0.y,h0.z,h0.w},{h1.x,h1.y,h1.z,h1.w},
                                {h2.x,h2.y,h2.z,h2.w},{h3.x,h3.y,h3.z,h3.w}};
        #pragma unroll
        for (int jj = 0; jj < 4; ++jj) {
            const float4 wA = *(const float4*)&W1s[j + jj][hb];
            const float4 wB = *(const float4*)&W1s[j + jj][hb + 4];
            const float wv8[8] = {wA.x,wA.y,wA.z,wA.w,wB.x,wB.y,wB.z,wB.w};
            #pragma unroll
            for (int i = 0; i < 4; ++i)
                #pragma unroll
                for (int q = 0; q < 8; ++q)
                    acc[i][q] = fmaf(hv[i][jj], wv8[q], acc[i][q]);
        }
    }
    float c18[8];
    #pragma unroll
    for (int q = 0; q < 8; ++q) c18[q] = c1[hb + q];
    #pragma unroll
    for (int i = 0; i < 4; ++i) {
        const size_t tokg = tok0 + tb + i;
        float r[8];
        #pragma unroll
        for (int q = 0; q < 8; ++q) r[q] = gelu_exact(acc[i][q] + c18[q]);
        float4 s0 = {r[0], r[1], r[2], r[3]};
        float4 s1 = {r[4], r[5], r[6], r[7]};
        float* dst = &y_ws[tokg * 256 + hb];
        *(float4*)dst = s0;
        *(float4*)(dst + 4) = s1;
    }
}

// ============ Kernel D: depthwise 3x3 + GELU + bf16 MFMA W2 + residual =======
__global__ __launch_bounds__(256) void kD(
    const float* __restrict__ y_ws, const float* __restrict__ Wdw, const float* __restrict__ bdw,
    const float* __restrict__ W2, const float* __restrict__ c2,
    float* __restrict__ out)
{
    __shared__ unsigned short W2T[64 * 256];   // bf16, transposed [col][k], XOR-swizzled (32 KB)
    __shared__ unsigned short zsb2[PIXD * 256]; // bf16 [pix][k], XOR-swizzled (8 KB)
    const int t = threadIdx.x;
    const int bid = blockIdx.x;                 // 2 * 128 * 16 = 4096 blocks
    const int b = bid >> 11;                    // 2048 per batch
    const int rem = bid & 2047;
    const int hh = rem >> 4;                    // 16 strips per row
    const int ww0 = (rem & 15) * PIXD;

    // stage W2 -> bf16, transposed, swizzled. thread handles (c, k2) pairs.
    #pragma unroll 4
    for (int i = 0; i < 32; ++i) {
        const int p = t + i * 256;             // p < 8192
        const int c = p & 63, k2 = p >> 6;     // k = 2*k2
        const float w0 = W2[(size_t)(2 * k2) * 64 + c];
        const float w1 = W2[(size_t)(2 * k2 + 1) * 64 + c];
        const unsigned int pk = (unsigned int)f2bf(w0) | ((unsigned int)f2bf(w1) << 16);
        const unsigned int uidx = ((unsigned int)(c * 128 + k2)) ^ (((unsigned int)(c & 7)) << 2);
        ((unsigned int*)W2T)[uidx] = pk;
    }

    // phase 1: depthwise conv, thread = channel, slide over PIXD pixels
    {
        const float* __restrict__ yb = y_ws + (size_t)b * HWq * 256;
        float wd[9];
        #pragma unroll
        for (int q = 0; q < 9; ++q) wd[q] = Wdw[t * 9 + q];
        const float bdv = bdw[t];
        const bool r0ok = (hh > 0), r2ok = (hh < Hq - 1);
        const int y0r = (hh - 1) << 8, y1r = hh << 8, y2r = (hh + 1) << 8;

        float u0[3], u1[3], u2[3];
        {
            const int xm = (ww0 - 1) & 255, xc = ww0;
            u0[0] = r0ok ? yb[(size_t)(y0r + xm) * 256 + t] : 0.0f;
            u0[1] =        yb[(size_t)(y1r + xm) * 256 + t];
            u0[2] = r2ok ? yb[(size_t)(y2r + xm) * 256 + t] : 0.0f;
            u1[0] = r0ok ? yb[(size_t)(y0r + xc) * 256 + t] : 0.0f;
            u1[1] =        yb[(size_t)(y1r + xc) * 256 + t];
            u1[2] = r2ok ? yb[(size_t)(y2r + xc) * 256 + t] : 0.0f;
        }
        #pragma unroll 4
        for (int p = 0; p < PIXD; ++p) {
            const int xp = (ww0 + p + 1) & 255;
            u2[0] = r0ok ? yb[(size_t)(y0r + xp) * 256 + t] : 0.0f;
            u2[1] =        yb[(size_t)(y1r + xp) * 256 + t];
            u2[2] = r2ok ? yb[(size_t)(y2r + xp) * 256 + t] : 0.0f;
            float a = bdv;
            a = fmaf(wd[0], u0[0], a); a = fmaf(wd[1], u1[0], a); a = fmaf(wd[2], u2[0], a);
            a = fmaf(wd[3], u0[1], a); a = fmaf(wd[4], u1[1], a); a = fmaf(wd[5], u2[1], a);
            a = fmaf(wd[6], u0[2], a); a = fmaf(wd[7], u1[2], a); a = fmaf(wd[8], u2[2], a);
            zsb2[(p * 256 + t) ^ ((p & 7) << 3)] = f2bf(gelu_exact(a));
            u0[0] = u1[0]; u0[1] = u1[1]; u0[2] = u1[2];
            u1[0] = u2[0]; u1[1] = u2[1]; u1[2] = u2[2];
        }
    }
    __syncthreads();

    // phase 2: z(16x256) @ W2(256x64) via mfma_f32_16x16x32_bf16.
    // wave wv owns output cols [wv*16, wv*16+16). A=z rows(pix), B=W2T cols.
    const int lane = t & 63, wv = t >> 6;
    const int fr = lane & 15;                 // A-row / B-col / C-col index
    const int kb = (lane >> 4) * 8;           // k sub-offset per 16-lane group
    const int col = wv * 16 + fr;
    f32x4v acc = {0.0f, 0.0f, 0.0f, 0.0f};
    #pragma unroll
    for (int kk = 0; kk < 8; ++kk) {
        const int ka = kk * 32 + kb;
        const short8v af = *(const short8v*)&zsb2[(fr * 256 + ka) ^ ((fr & 7) << 3)];
        const short8v bf = *(const short8v*)&W2T[(col * 256 + ka) ^ ((col & 7) << 3)];
        acc = __builtin_amdgcn_mfma_f32_16x16x32_bf16(af, bf, acc, 0, 0, 0);
    }
    // C layout: col = lane&15, row(pix) = (lane>>4)*4 + r
    const float c2v = c2[col];
    #pragma unroll
    for (int r = 0; r < 4; ++r) {
        const int pix = (lane >> 4) * 4 + r;
        const size_t tokg = (size_t)b * HWq + ((size_t)hh << 8) + ww0 + pix;
        out[tokg * 64 + col] += acc[r] + c2v;
    }
}

extern "C" void kernel_launch(void* const* d_in, const int* in_sizes, int n_in,
                              void* d_out, int out_size, void* d_ws, size_t ws_size,
                              hipStream_t stream) {
    const float* x    = (const float*)d_in[0];
    const float* ref  = (const float*)d_in[1];
    const float* g1   = (const float*)d_in[2];
    const float* be1  = (const float*)d_in[3];
    const float* g2   = (const float*)d_in[4];
    const float* be2  = (const float*)d_in[5];
    const float* Woff = (const float*)d_in[6];
    const float* boff = (const float*)d_in[7];
    const float* Wa   = (const float*)d_in[8];
    const float* ba   = (const float*)d_in[9];
    const float* Wv   = (const float*)d_in[10];
    const float* bv   = (const float*)d_in[11];
    const float* Wo   = (const float*)d_in[12];
    const float* bo   = (const float*)d_in[13];
    const float* W1   = (const float*)d_in[14];
    const float* c1   = (const float*)d_in[15];
    const float* Wdw  = (const float*)d_in[16];
    const float* bdw  = (const float*)d_in[17];
    const float* W2   = (const float*)d_in[18];
    const float* c2   = (const float*)d_in[19];

    float* out = (float*)d_out;
    float* ws = (float*)d_ws;
    float* v_ws    = ws;                                   // B*2*HW*32
    float* loc_ws  = v_ws  + (size_t)Bq * 2 * HWq * 32;    // NTOK*36
    float* attn_ws = loc_ws + (size_t)NTOK * 36;           // NTOK*18
    float* y_ws    = attn_ws + (size_t)NTOK * 18;          // NTOK*256

    hipLaunchKernelGGL(kA, dim3(NTOK / TOKA), dim3(256), 0, stream,
                       x, ref, g1, be1, Woff, boff, Wa, ba, Wv, bv,
                       v_ws, loc_ws, attn_ws);
    hipLaunchKernelGGL(kB, dim3(NTOK / TOKB), dim3(256), 0, stream,
                       x, v_ws, loc_ws, attn_ws, Wo, bo, out);
    hipLaunchKernelGGL(kC, dim3(NTOK / TOKC), dim3(256), 0, stream,
                       out, g2, be2, W1, c1, y_ws);
    hipLaunchKernelGGL(kD, dim3(Bq * Hq * (Wq / PIXD)), dim3(256), 0, stream,
                       y_ws, Wdw, bdw, W2, c2, out);
}

// Round 5
// 184.953 us; speedup vs baseline: 2.9998x; 1.1531x over previous
//
#include <hip/hip_runtime.h>
#include <math.h>

#define Bq 2
#define Hq 128
#define Wq 256
#define Cq 64
#define HIDq 256
#define HWq (Hq * Wq)
#define NTOK (Bq * HWq)

#define TOKA 128
#define TOKB 32
#define TOKC 32
#define PIXD 16

typedef __attribute__((ext_vector_type(8))) short short8v;
typedef __attribute__((ext_vector_type(4))) float f32x4v;

__device__ inline float wave_reduce_sum(float v) {
    #pragma unroll
    for (int m = 1; m < 64; m <<= 1) v += __shfl_xor(v, m, 64);
    return v;
}

__device__ inline float gelu_exact(float x) {
    return 0.5f * x * (1.0f + erff(x * 0.70710678118654752440f));
}

__device__ inline unsigned short f2bf(float f) {
    unsigned int u = __float_as_uint(f);
    u += 0x7FFFu + ((u >> 16) & 1u);
    return (unsigned short)(u >> 16);
}

// ============ Kernel A: LN1 + fused {Wv | Woff | Wa} GEMM, softmax, loc ======
// 512 threads, 128 tokens/block. Flat LDS: Wc[64][120] | hsb[128][68] | logit[128][20]
__global__ __launch_bounds__(512, 4) void kA(
    const float* __restrict__ x, const float* __restrict__ ref,
    const float* __restrict__ g1, const float* __restrict__ be1,
    const float* __restrict__ Woff, const float* __restrict__ boff,
    const float* __restrict__ Wa, const float* __restrict__ ba,
    const float* __restrict__ Wv, const float* __restrict__ bv,
    float* __restrict__ v_ws, float* __restrict__ loc_ws, float* __restrict__ attn_ws)
{
    __shared__ float lds[64 * 120 + TOKA * 68 + TOKA * 20];
#define WcF(j, c)   lds[(j) * 120 + (c)]
#define HSB(tk, ch) lds[7680 + (tk) * 68 + (ch)]
#define LG(tk, kk)  lds[7680 + TOKA * 68 + (tk) * 20 + (kk)]
    const int t = threadIdx.x;
    const int tok0 = blockIdx.x * TOKA;
    const int b = tok0 >> 15;          // HW = 32768
    const int pix0 = tok0 & (HWq - 1);

    // ---- stage fused weight matrix (cols: 0..63 Wv, 64..99 Woff, 100..117 Wa)
    for (int idx = t; idx < 64 * 120; idx += 512) {
        const int j = idx / 120, c = idx - j * 120;
        float w = 0.0f;
        if (c < 64) w = Wv[j * 64 + c];
        else if (c < 100) w = Woff[j * 36 + (c - 64)];
        else if (c < 118) w = Wa[j * 18 + (c - 100)];
        WcF(j, c) = w;
    }

    // ---- LayerNorm: thread = (token, quarter). Coalesced loads, 2-step shuffle.
    {
        const int tok = t >> 2, part = t & 3;
        const int chb = part * 16;
        const float* xp = x + (size_t)(tok0 + tok) * 64 + chb;
        const float4 v0 = ((const float4*)xp)[0];
        const float4 v1 = ((const float4*)xp)[1];
        const float4 v2 = ((const float4*)xp)[2];
        const float4 v3 = ((const float4*)xp)[3];
        float s = ((v0.x + v0.y) + (v0.z + v0.w)) + ((v1.x + v1.y) + (v1.z + v1.w))
                + ((v2.x + v2.y) + (v2.z + v2.w)) + ((v3.x + v3.y) + (v3.z + v3.w));
        float s2 = 0.0f;
        s2 = fmaf(v0.x, v0.x, s2); s2 = fmaf(v0.y, v0.y, s2);
        s2 = fmaf(v0.z, v0.z, s2); s2 = fmaf(v0.w, v0.w, s2);
        s2 = fmaf(v1.x, v1.x, s2); s2 = fmaf(v1.y, v1.y, s2);
        s2 = fmaf(v1.z, v1.z, s2); s2 = fmaf(v1.w, v1.w, s2);
        s2 = fmaf(v2.x, v2.x, s2); s2 = fmaf(v2.y, v2.y, s2);
        s2 = fmaf(v2.z, v2.z, s2); s2 = fmaf(v2.w, v2.w, s2);
        s2 = fmaf(v3.x, v3.x, s2); s2 = fmaf(v3.y, v3.y, s2);
        s2 = fmaf(v3.z, v3.z, s2); s2 = fmaf(v3.w, v3.w, s2);
        s  += __shfl_xor(s, 1);  s2 += __shfl_xor(s2, 1);
        s  += __shfl_xor(s, 2);  s2 += __shfl_xor(s2, 2);
        const float m  = s * (1.0f / 64.0f);
        const float var = fmaf(-m, m, s2 * (1.0f / 64.0f));
        const float rs = rsqrtf(var + 1e-5f);
        const float nb = -m * rs;
        const float4 gA = *(const float4*)(g1 + chb),     gB = *(const float4*)(g1 + chb + 4);
        const float4 gC = *(const float4*)(g1 + chb + 8), gD = *(const float4*)(g1 + chb + 12);
        const float4 bA = *(const float4*)(be1 + chb),     bB = *(const float4*)(be1 + chb + 4);
        const float4 bC = *(const float4*)(be1 + chb + 8), bD = *(const float4*)(be1 + chb + 12);
        float4* hrow = (float4*)&HSB(tok, chb);
        float4 h0 = {fmaf(fmaf(v0.x, rs, nb), gA.x, bA.x), fmaf(fmaf(v0.y, rs, nb), gA.y, bA.y),
                     fmaf(fmaf(v0.z, rs, nb), gA.z, bA.z), fmaf(fmaf(v0.w, rs, nb), gA.w, bA.w)};
        float4 h1 = {fmaf(fmaf(v1.x, rs, nb), gB.x, bB.x), fmaf(fmaf(v1.y, rs, nb), gB.y, bB.y),
                     fmaf(fmaf(v1.z, rs, nb), gB.z, bB.z), fmaf(fmaf(v1.w, rs, nb), gB.w, bB.w)};
        float4 h2 = {fmaf(fmaf(v2.x, rs, nb), gC.x, bC.x), fmaf(fmaf(v2.y, rs, nb), gC.y, bC.y),
                     fmaf(fmaf(v2.z, rs, nb), gC.z, bC.z), fmaf(fmaf(v2.w, rs, nb), gC.w, bC.w)};
        float4 h3 = {fmaf(fmaf(v3.x, rs, nb), gD.x, bD.x), fmaf(fmaf(v3.y, rs, nb), gD.y, bD.y),
                     fmaf(fmaf(v3.z, rs, nb), gD.z, bD.z), fmaf(fmaf(v3.w, rs, nb), gD.w, bD.w)};
        hrow[0] = h0; hrow[1] = h1; hrow[2] = h2; hrow[3] = h3;
    }
    __syncthreads();

    // ---- GEMM: 32 token-groups x 16 col-groups; lane owns cols {cg*4..+3, 64+cg*4..+3}
    const int cg = t & 15, tg = t >> 4;
    const int tb = tg * 4;
    const int c0 = cg * 4;
    float acc[4][8];
    #pragma unroll
    for (int i = 0; i < 4; ++i)
        #pragma unroll
        for (int q = 0; q < 8; ++q) acc[i][q] = 0.0f;

    for (int j = 0; j < 64; j += 4) {
        const float4 h0 = *(const float4*)&HSB(tb + 0, j);
        const float4 h1 = *(const float4*)&HSB(tb + 1, j);
        const float4 h2 = *(const float4*)&HSB(tb + 2, j);
        const float4 h3 = *(const float4*)&HSB(tb + 3, j);
        const float hv[4][4] = {{h0.x,h0.y,h0.z,h0.w},{h1.x,h1.y,h1.z,h1.w},
                                {h2.x,h2.y,h2.z,h2.w},{h3.x,h3.y,h3.z,h3.w}};
        #pragma unroll
        for (int jj = 0; jj < 4; ++jj) {
            const float4 wA = *(const float4*)&WcF(j + jj, c0);
            const float4 wB = *(const float4*)&WcF(j + jj, 64 + c0);
            const float wv8[8] = {wA.x,wA.y,wA.z,wA.w,wB.x,wB.y,wB.z,wB.w};
            #pragma unroll
            for (int i = 0; i < 4; ++i)
                #pragma unroll
                for (int q = 0; q < 8; ++q)
                    acc[i][q] = fmaf(hv[i][jj], wv8[q], acc[i][q]);
        }
    }

    // ---- epilogue: v -> global (one float4/token), off -> loc direct, attn -> LDS
    {
        const int n = c0 >> 5, cc = c0 & 31;
        const float4 bv4 = *(const float4*)&bv[c0];
        #pragma unroll
        for (int i = 0; i < 4; ++i) {
            const int pix = pix0 + tb + i;
            float4 o = {acc[i][0] + bv4.x, acc[i][1] + bv4.y,
                        acc[i][2] + bv4.z, acc[i][3] + bv4.w};
            *(float4*)&v_ws[((size_t)(b * 2 + n) * HWq + pix) * 32 + cc] = o;
        }
    }
    if (cg <= 8) {                        // off cols 64..99 -> loc = ref + off + boff
        const int co0 = c0;               // 0..32
        #pragma unroll
        for (int i = 0; i < 4; ++i) {
            const size_t tokg = (size_t)tok0 + tb + i;
            #pragma unroll
            for (int q = 0; q < 4; ++q) {
                const int co = co0 + q;
                const int rco = (co >= 18) ? co - 18 : co;
                loc_ws[tokg * 36 + co] = ref[tokg * 18 + rco] + acc[i][4 + q] + boff[co];
            }
        }
    } else if (cg <= 13) {                // attn logit cols 100..117
        #pragma unroll
        for (int q = 0; q < 4; ++q) {
            const int c = 64 + c0 + q;
            if (c < 118) {
                const float bav = ba[c - 100];
                #pragma unroll
                for (int i = 0; i < 4; ++i) LG(tb + i, c - 100) = acc[i][4 + q] + bav;
            }
        }
    }
    __syncthreads();

    // ---- softmax per (token, head)
    if (t < TOKA * 2) {
        const int tk = t >> 1, head = t & 1;
        float mx = -1e30f;
        #pragma unroll
        for (int k = 0; k < 9; ++k) mx = fmaxf(mx, LG(tk, head * 9 + k));
        float e[9], s = 0.0f;
        #pragma unroll
        for (int k = 0; k < 9; ++k) { e[k] = expf(LG(tk, head * 9 + k) - mx); s += e[k]; }
        const float inv = 1.0f / s;
        float* dst = &attn_ws[(size_t)(tok0 + tk) * 18 + head * 9];
        #pragma unroll
        for (int k = 0; k < 9; ++k) dst[k] = e[k] * inv;
    }
#undef WcF
#undef HSB
#undef LG
}

// ============ Kernel B: bilinear sample + attn + Wo + residual ===============
__global__ __launch_bounds__(256) void kB(
    const float* __restrict__ x, const float* __restrict__ v_ws,
    const float* __restrict__ loc_ws, const float* __restrict__ attn_ws,
    const float* __restrict__ Wo, const float* __restrict__ bo,
    float* __restrict__ out)
{
    __shared__ float sout[TOKB][68];
    __shared__ float loc_s[TOKB][36];
    __shared__ float attn_s[TOKB][18];
    const int t = threadIdx.x;
    // XCD-chunked swizzle: 2048 blocks, 8 XCDs, 256 contiguous blocks per XCD
    const int bid = (blockIdx.x & 7) * (NTOK / TOKB / 8) + (blockIdx.x >> 3);
    const int tok0 = bid * TOKB;
    const int b = tok0 >> 15;

    for (int i4 = t; i4 < TOKB * 36 / 4; i4 += 256)
        ((float4*)loc_s)[i4] = ((const float4*)(loc_ws + (size_t)tok0 * 36))[i4];
    for (int i4 = t; i4 < TOKB * 18 / 4; i4 += 256)
        ((float4*)attn_s)[i4] = ((const float4*)(attn_ws + (size_t)tok0 * 18))[i4];
    __syncthreads();

    // sampling: wave handles 8 tokens, lane = channel (n, cc)
    const int lane = t & 63, wvid = t >> 6;
    const int n = lane >> 5, cc = lane & 31;
    const float* __restrict__ vimg = v_ws + (size_t)(b * 2 + n) * HWq * 32;
    #pragma unroll 2
    for (int i = 0; i < 8; ++i) {
        const int tk = wvid * 8 + i;
        float accs = 0.0f;
        #pragma unroll
        for (int k = 0; k < 9; ++k) {
            const float gx = loc_s[tk][n * 18 + k * 2 + 0];
            const float gy = loc_s[tk][n * 18 + k * 2 + 1];
            const float a  = attn_s[tk][n * 9 + k];
            const float ix = fmaf(gx, 128.0f, 127.5f);   // (gx+1)*128 - 0.5
            const float iy = fmaf(gy, 64.0f, 63.5f);     // (gy+1)*64 - 0.5
            const float x0f = floorf(ix), y0f = floorf(iy);
            const float wx1 = ix - x0f, wy1 = iy - y0f;
            const float wx0 = 1.0f - wx1, wy0 = 1.0f - wy1;
            const int x0 = (int)x0f, y0 = (int)y0f;
            const int x1i = x0 + 1, y1i = y0 + 1;
            const int x0c = min(max(x0, 0), Wq - 1), y0c = min(max(y0, 0), Hq - 1);
            const int x1c = min(max(x1i, 0), Wq - 1), y1c = min(max(y1i, 0), Hq - 1);
            const bool vx0 = (x0 >= 0) & (x0 <= Wq - 1);
            const bool vy0 = (y0 >= 0) & (y0 <= Hq - 1);
            const bool vx1 = (x1i >= 0) & (x1i <= Wq - 1);
            const bool vy1 = (y1i >= 0) & (y1i <= Hq - 1);
            // 4 independent, unconditional (clamped) gathers
            const float v00 = vimg[(((y0c << 8) + x0c) << 5) + cc];
            const float v10 = vimg[(((y0c << 8) + x1c) << 5) + cc];
            const float v01 = vimg[(((y1c << 8) + x0c) << 5) + cc];
            const float v11 = vimg[(((y1c << 8) + x1c) << 5) + cc];
            float s = 0.0f;
            s = fmaf((vx0 && vy0) ? wx0 * wy0 : 0.0f, v00, s);
            s = fmaf((vx1 && vy0) ? wx1 * wy0 : 0.0f, v10, s);
            s = fmaf((vx0 && vy1) ? wx0 * wy1 : 0.0f, v01, s);
            s = fmaf((vx1 && vy1) ? wx1 * wy1 : 0.0f, v11, s);
            accs = fmaf(a, s, accs);
        }
        sout[tk][lane] = accs;
    }
    __syncthreads();

    // Wo GEMM: 2 tok x 4 col tile, Wo streamed through L1 (16 KB, broadcast)
    const int cg = t & 15, tg = t >> 4;
    const int cb = cg * 4, tb = tg * 2;
    float acc[2][4];
    #pragma unroll
    for (int i = 0; i < 2; ++i)
        #pragma unroll
        for (int q = 0; q < 4; ++q) acc[i][q] = 0.0f;

    for (int j = 0; j < 64; j += 4) {
        const float4 h0 = *(const float4*)&sout[tb + 0][j];
        const float4 h1 = *(const float4*)&sout[tb + 1][j];
        const float hv[2][4] = {{h0.x,h0.y,h0.z,h0.w},{h1.x,h1.y,h1.z,h1.w}};
        #pragma unroll
        for (int jj = 0; jj < 4; ++jj) {
            const float4 w = *(const float4*)&Wo[(size_t)(j + jj) * 64 + cb];
            const float wv4[4] = {w.x, w.y, w.z, w.w};
            #pragma unroll
            for (int i = 0; i < 2; ++i)
                #pragma unroll
                for (int q = 0; q < 4; ++q)
                    acc[i][q] = fmaf(hv[i][jj], wv4[q], acc[i][q]);
        }
    }
    const float4 bo4 = *(const float4*)&bo[cb];
    #pragma unroll
    for (int i = 0; i < 2; ++i) {
        const size_t tokg = (size_t)tok0 + tb + i;
        const float4 r = *(const float4*)&x[tokg * 64 + cb];
        float4 o = {acc[i][0]+bo4.x+r.x, acc[i][1]+bo4.y+r.y,
                    acc[i][2]+bo4.z+r.z, acc[i][3]+bo4.w+r.w};
        *(float4*)&out[tokg * 64 + cb] = o;
    }
}

// ============ Kernel C: LN2 + W1 + GELU ======================================
__global__ __launch_bounds__(256) void kC(
    const float* __restrict__ x1, const float* __restrict__ g2, const float* __restrict__ be2,
    const float* __restrict__ W1, const float* __restrict__ c1,
    float* __restrict__ y_ws)
{
    __shared__ float W1s[64][256];
    __shared__ float hs2[TOKC][68];
    const int t = threadIdx.x;
    const int tok0 = blockIdx.x * TOKC;

    for (int i4 = t; i4 < 64 * 256 / 4; i4 += 256)
        ((float4*)W1s)[i4] = ((const float4*)W1)[i4];

    const int lane = t & 63, wvid = t >> 6;
    const float gv = g2[lane], bev = be2[lane];
    for (int i = 0; i < TOKC / 4; ++i) {
        const int tk = wvid * (TOKC / 4) + i;
        float xv = x1[(size_t)(tok0 + tk) * 64 + lane];
        float m = wave_reduce_sum(xv) * (1.0f / 64.0f);
        float d = xv - m;
        float var = wave_reduce_sum(d * d) * (1.0f / 64.0f);
        hs2[tk][lane] = d * rsqrtf(var + 1e-5f) * gv + bev;
    }
    __syncthreads();

    // GEMM: 4 tok x 8 hid tile (32 tok x 256 hid per block)
    const int cg = t & 31, tg = t >> 5;
    const int hb = cg * 8, tb = tg * 4;
    float acc[4][8];
    #pragma unroll
    for (int i = 0; i < 4; ++i)
        #pragma unroll
        for (int q = 0; q < 8; ++q) acc[i][q] = 0.0f;

    for (int j = 0; j < 64; j += 4) {
        const float4 h0 = *(const float4*)&hs2[tb + 0][j];
        const float4 h1 = *(const float4*)&hs2[tb + 1][j];
        const float4 h2 = *(const float4*)&hs2[tb + 2][j];
        const float4 h3 = *(const float4*)&hs2[tb + 3][j];
        const float hv[4][4] = {{h0.x,h0.y,h0.z,h0.w},{h1.x,h1.y,h1.z,h1.w},
                                {h2.x,h2.y,h2.z,h2.w},{h3.x,h3.y,h3.z,h3.w}};
        #pragma unroll
        for (int jj = 0; jj < 4; ++jj) {
            const float4 wA = *(const float4*)&W1s[j + jj][hb];
            const float4 wB = *(const float4*)&W1s[j + jj][hb + 4];
            const float wv8[8] = {wA.x,wA.y,wA.z,wA.w,wB.x,wB.y,wB.z,wB.w};
            #pragma unroll
            for (int i = 0; i < 4; ++i)
                #pragma unroll
                for (int q = 0; q < 8; ++q)
                    acc[i][q] = fmaf(hv[i][jj], wv8[q], acc[i][q]);
        }
    }
    float c18[8];
    #pragma unroll
    for (int q = 0; q < 8; ++q) c18[q] = c1[hb + q];
    #pragma unroll
    for (int i = 0; i < 4; ++i) {
        const size_t tokg = tok0 + tb + i;
        float r[8];
        #pragma unroll
        for (int q = 0; q < 8; ++q) r[q] = gelu_exact(acc[i][q] + c18[q]);
        float4 s0 = {r[0], r[1], r[2], r[3]};
        float4 s1 = {r[4], r[5], r[6], r[7]};
        float* dst = &y_ws[tokg * 256 + hb];
        *(float4*)dst = s0;
        *(float4*)(dst + 4) = s1;
    }
}

// ============ Kernel D: depthwise 3x3 + GELU + bf16 MFMA W2 + residual =======
__global__ __launch_bounds__(256) void kD(
    const float* __restrict__ y_ws, const float* __restrict__ Wdw, const float* __restrict__ bdw,
    const float* __restrict__ W2, const float* __restrict__ c2,
    float* __restrict__ out)
{
    __shared__ unsigned short W2T[64 * 256];   // bf16, transposed [col][k], XOR-swizzled (32 KB)
    __shared__ unsigned short zsb2[PIXD * 256]; // bf16 [pix][k], XOR-swizzled (8 KB)
    const int t = threadIdx.x;
    const int bid = blockIdx.x;                 // 2 * 128 * 16 = 4096 blocks
    const int b = bid >> 11;                    // 2048 per batch
    const int rem = bid & 2047;
    const int hh = rem >> 4;                    // 16 strips per row
    const int ww0 = (rem & 15) * PIXD;

    // stage W2 -> bf16, transposed, swizzled. thread handles (c, k2) pairs.
    #pragma unroll 4
    for (int i = 0; i < 32; ++i) {
        const int p = t + i * 256;             // p < 8192
        const int c = p & 63, k2 = p >> 6;     // k = 2*k2
        const float w0 = W2[(size_t)(2 * k2) * 64 + c];
        const float w1 = W2[(size_t)(2 * k2 + 1) * 64 + c];
        const unsigned int pk = (unsigned int)f2bf(w0) | ((unsigned int)f2bf(w1) << 16);
        const unsigned int uidx = ((unsigned int)(c * 128 + k2)) ^ (((unsigned int)(c & 7)) << 2);
        ((unsigned int*)W2T)[uidx] = pk;
    }

    // phase 1: depthwise conv, thread = channel, slide over PIXD pixels
    {
        const float* __restrict__ yb = y_ws + (size_t)b * HWq * 256;
        float wd[9];
        #pragma unroll
        for (int q = 0; q < 9; ++q) wd[q] = Wdw[t * 9 + q];
        const float bdv = bdw[t];
        const bool r0ok = (hh > 0), r2ok = (hh < Hq - 1);
        const int y0r = (hh - 1) << 8, y1r = hh << 8, y2r = (hh + 1) << 8;

        float u0[3], u1[3], u2[3];
        {
            const int xm = (ww0 - 1) & 255, xc = ww0;
            u0[0] = r0ok ? yb[(size_t)(y0r + xm) * 256 + t] : 0.0f;
            u0[1] =        yb[(size_t)(y1r + xm) * 256 + t];
            u0[2] = r2ok ? yb[(size_t)(y2r + xm) * 256 + t] : 0.0f;
            u1[0] = r0ok ? yb[(size_t)(y0r + xc) * 256 + t] : 0.0f;
            u1[1] =        yb[(size_t)(y1r + xc) * 256 + t];
            u1[2] = r2ok ? yb[(size_t)(y2r + xc) * 256 + t] : 0.0f;
        }
        #pragma unroll 4
        for (int p = 0; p < PIXD; ++p) {
            const int xp = (ww0 + p + 1) & 255;
            u2[0] = r0ok ? yb[(size_t)(y0r + xp) * 256 + t] : 0.0f;
            u2[1] =        yb[(size_t)(y1r + xp) * 256 + t];
            u2[2] = r2ok ? yb[(size_t)(y2r + xp) * 256 + t] : 0.0f;
            float a = bdv;
            a = fmaf(wd[0], u0[0], a); a = fmaf(wd[1], u1[0], a); a = fmaf(wd[2], u2[0], a);
            a = fmaf(wd[3], u0[1], a); a = fmaf(wd[4], u1[1], a); a = fmaf(wd[5], u2[1], a);
            a = fmaf(wd[6], u0[2], a); a = fmaf(wd[7], u1[2], a); a = fmaf(wd[8], u2[2], a);
            zsb2[(p * 256 + t) ^ ((p & 7) << 3)] = f2bf(gelu_exact(a));
            u0[0] = u1[0]; u0[1] = u1[1]; u0[2] = u1[2];
            u1[0] = u2[0]; u1[1] = u2[1]; u1[2] = u2[2];
        }
    }
    __syncthreads();

    // phase 2: z(16x256) @ W2(256x64) via mfma_f32_16x16x32_bf16.
    // wave wv owns output cols [wv*16, wv*16+16). A=z rows(pix), B=W2T cols.
    const int lane = t & 63, wv = t >> 6;
    const int fr = lane & 15;                 // A-row / B-col / C-col index
    const int kb = (lane >> 4) * 8;           // k sub-offset per 16-lane group
    const int col = wv * 16 + fr;
    f32x4v acc = {0.0f, 0.0f, 0.0f, 0.0f};
    #pragma unroll
    for (int kk = 0; kk < 8; ++kk) {
        const int ka = kk * 32 + kb;
        const short8v af = *(const short8v*)&zsb2[(fr * 256 + ka) ^ ((fr & 7) << 3)];
        const short8v bf = *(const short8v*)&W2T[(col * 256 + ka) ^ ((col & 7) << 3)];
        acc = __builtin_amdgcn_mfma_f32_16x16x32_bf16(af, bf, acc, 0, 0, 0);
    }
    // C layout: col = lane&15, row(pix) = (lane>>4)*4 + r
    const float c2v = c2[col];
    #pragma unroll
    for (int r = 0; r < 4; ++r) {
        const int pix = (lane >> 4) * 4 + r;
        const size_t tokg = (size_t)b * HWq + ((size_t)hh << 8) + ww0 + pix;
        out[tokg * 64 + col] += acc[r] + c2v;
    }
}

extern "C" void kernel_launch(void* const* d_in, const int* in_sizes, int n_in,
                              void* d_out, int out_size, void* d_ws, size_t ws_size,
                              hipStream_t stream) {
    const float* x    = (const float*)d_in[0];
    const float* ref  = (const float*)d_in[1];
    const float* g1   = (const float*)d_in[2];
    const float* be1  = (const float*)d_in[3];
    const float* g2   = (const float*)d_in[4];
    const float* be2  = (const float*)d_in[5];
    const float* Woff = (const float*)d_in[6];
    const float* boff = (const float*)d_in[7];
    const float* Wa   = (const float*)d_in[8];
    const float* ba   = (const float*)d_in[9];
    const float* Wv   = (const float*)d_in[10];
    const float* bv   = (const float*)d_in[11];
    const float* Wo   = (const float*)d_in[12];
    const float* bo   = (const float*)d_in[13];
    const float* W1   = (const float*)d_in[14];
    const float* c1   = (const float*)d_in[15];
    const float* Wdw  = (const float*)d_in[16];
    const float* bdw  = (const float*)d_in[17];
    const float* W2   = (const float*)d_in[18];
    const float* c2   = (const float*)d_in[19];

    float* out = (float*)d_out;
    float* ws = (float*)d_ws;
    float* v_ws    = ws;                                   // B*2*HW*32
    float* loc_ws  = v_ws  + (size_t)Bq * 2 * HWq * 32;    // NTOK*36
    float* attn_ws = loc_ws + (size_t)NTOK * 36;           // NTOK*18
    float* y_ws    = attn_ws + (size_t)NTOK * 18;          // NTOK*256

    hipLaunchKernelGGL(kA, dim3(NTOK / TOKA), dim3(512), 0, stream,
                       x, ref, g1, be1, Woff, boff, Wa, ba, Wv, bv,
                       v_ws, loc_ws, attn_ws);
    hipLaunchKernelGGL(kB, dim3(NTOK / TOKB), dim3(256), 0, stream,
                       x, v_ws, loc_ws, attn_ws, Wo, bo, out);
    hipLaunchKernelGGL(kC, dim3(NTOK / TOKC), dim3(256), 0, stream,
                       out, g2, be2, W1, c1, y_ws);
    hipLaunchKernelGGL(kD, dim3(Bq * Hq * (Wq / PIXD)), dim3(256), 0, stream,
                       y_ws, Wdw, bdw, W2, c2, out);
}

// Round 6
// 181.672 us; speedup vs baseline: 3.0540x; 1.0181x over previous
//
#include <hip/hip_runtime.h>
#include <math.h>

#define Bq 2
#define Hq 128
#define Wq 256
#define Cq 64
#define HIDq 256
#define HWq (Hq * Wq)
#define NTOK (Bq * HWq)

#define TOKA 128
#define TOKB 32
#define TOKC 64
#define PIXD 32

typedef __attribute__((ext_vector_type(8))) short short8v;
typedef __attribute__((ext_vector_type(4))) float f32x4v;

__device__ inline float gelu_exact(float x) {
    return 0.5f * x * (1.0f + erff(x * 0.70710678118654752440f));
}

__device__ inline unsigned short f2bf(float f) {
    unsigned int u = __float_as_uint(f);
    u += 0x7FFFu + ((u >> 16) & 1u);
    return (unsigned short)(u >> 16);
}

__device__ inline float bf2f(unsigned short u) {
    return __uint_as_float(((unsigned int)u) << 16);
}

// ============ Kernel A: LN1 + fused {Wv | Woff | Wa} GEMM, softmax, loc ======
// 512 threads, 128 tokens/block. Flat LDS: Wc[64][120] | hsb[128][68] | logit[128][20]
__global__ __launch_bounds__(512, 4) void kA(
    const float* __restrict__ x, const float* __restrict__ ref,
    const float* __restrict__ g1, const float* __restrict__ be1,
    const float* __restrict__ Woff, const float* __restrict__ boff,
    const float* __restrict__ Wa, const float* __restrict__ ba,
    const float* __restrict__ Wv, const float* __restrict__ bv,
    float* __restrict__ v_ws, float* __restrict__ loc_ws, float* __restrict__ attn_ws)
{
    __shared__ float lds[64 * 120 + TOKA * 68 + TOKA * 20];
#define WcF(j, c)   lds[(j) * 120 + (c)]
#define HSB(tk, ch) lds[7680 + (tk) * 68 + (ch)]
#define LG(tk, kk)  lds[7680 + TOKA * 68 + (tk) * 20 + (kk)]
    const int t = threadIdx.x;
    const int tok0 = blockIdx.x * TOKA;
    const int b = tok0 >> 15;          // HW = 32768
    const int pix0 = tok0 & (HWq - 1);

    // ---- stage fused weight matrix (cols: 0..63 Wv, 64..99 Woff, 100..117 Wa)
    for (int idx = t; idx < 64 * 120; idx += 512) {
        const int j = idx / 120, c = idx - j * 120;
        float w = 0.0f;
        if (c < 64) w = Wv[j * 64 + c];
        else if (c < 100) w = Woff[j * 36 + (c - 64)];
        else if (c < 118) w = Wa[j * 18 + (c - 100)];
        WcF(j, c) = w;
    }

    // ---- LayerNorm: thread = (token, quarter). Coalesced loads, 2-step shuffle.
    {
        const int tok = t >> 2, part = t & 3;
        const int chb = part * 16;
        const float* xp = x + (size_t)(tok0 + tok) * 64 + chb;
        const float4 v0 = ((const float4*)xp)[0];
        const float4 v1 = ((const float4*)xp)[1];
        const float4 v2 = ((const float4*)xp)[2];
        const float4 v3 = ((const float4*)xp)[3];
        float s = ((v0.x + v0.y) + (v0.z + v0.w)) + ((v1.x + v1.y) + (v1.z + v1.w))
                + ((v2.x + v2.y) + (v2.z + v2.w)) + ((v3.x + v3.y) + (v3.z + v3.w));
        float s2 = 0.0f;
        s2 = fmaf(v0.x, v0.x, s2); s2 = fmaf(v0.y, v0.y, s2);
        s2 = fmaf(v0.z, v0.z, s2); s2 = fmaf(v0.w, v0.w, s2);
        s2 = fmaf(v1.x, v1.x, s2); s2 = fmaf(v1.y, v1.y, s2);
        s2 = fmaf(v1.z, v1.z, s2); s2 = fmaf(v1.w, v1.w, s2);
        s2 = fmaf(v2.x, v2.x, s2); s2 = fmaf(v2.y, v2.y, s2);
        s2 = fmaf(v2.z, v2.z, s2); s2 = fmaf(v2.w, v2.w, s2);
        s2 = fmaf(v3.x, v3.x, s2); s2 = fmaf(v3.y, v3.y, s2);
        s2 = fmaf(v3.z, v3.z, s2); s2 = fmaf(v3.w, v3.w, s2);
        s  += __shfl_xor(s, 1);  s2 += __shfl_xor(s2, 1);
        s  += __shfl_xor(s, 2);  s2 += __shfl_xor(s2, 2);
        const float m  = s * (1.0f / 64.0f);
        const float var = fmaf(-m, m, s2 * (1.0f / 64.0f));
        const float rs = rsqrtf(var + 1e-5f);
        const float nb = -m * rs;
        const float4 gA = *(const float4*)(g1 + chb),     gB = *(const float4*)(g1 + chb + 4);
        const float4 gC = *(const float4*)(g1 + chb + 8), gD = *(const float4*)(g1 + chb + 12);
        const float4 bA = *(const float4*)(be1 + chb),     bB = *(const float4*)(be1 + chb + 4);
        const float4 bC = *(const float4*)(be1 + chb + 8), bD = *(const float4*)(be1 + chb + 12);
        float4* hrow = (float4*)&HSB(tok, chb);
        float4 h0 = {fmaf(fmaf(v0.x, rs, nb), gA.x, bA.x), fmaf(fmaf(v0.y, rs, nb), gA.y, bA.y),
                     fmaf(fmaf(v0.z, rs, nb), gA.z, bA.z), fmaf(fmaf(v0.w, rs, nb), gA.w, bA.w)};
        float4 h1 = {fmaf(fmaf(v1.x, rs, nb), gB.x, bB.x), fmaf(fmaf(v1.y, rs, nb), gB.y, bB.y),
                     fmaf(fmaf(v1.z, rs, nb), gB.z, bB.z), fmaf(fmaf(v1.w, rs, nb), gB.w, bB.w)};
        float4 h2 = {fmaf(fmaf(v2.x, rs, nb), gC.x, bC.x), fmaf(fmaf(v2.y, rs, nb), gC.y, bC.y),
                     fmaf(fmaf(v2.z, rs, nb), gC.z, bC.z), fmaf(fmaf(v2.w, rs, nb), gC.w, bC.w)};
        float4 h3 = {fmaf(fmaf(v3.x, rs, nb), gD.x, bD.x), fmaf(fmaf(v3.y, rs, nb), gD.y, bD.y),
                     fmaf(fmaf(v3.z, rs, nb), gD.z, bD.z), fmaf(fmaf(v3.w, rs, nb), gD.w, bD.w)};
        hrow[0] = h0; hrow[1] = h1; hrow[2] = h2; hrow[3] = h3;
    }
    __syncthreads();

    // ---- GEMM: 32 token-groups x 16 col-groups; lane owns cols {cg*4..+3, 64+cg*4..+3}
    const int cg = t & 15, tg = t >> 4;
    const int tb = tg * 4;
    const int c0 = cg * 4;
    float acc[4][8];
    #pragma unroll
    for (int i = 0; i < 4; ++i)
        #pragma unroll
        for (int q = 0; q < 8; ++q) acc[i][q] = 0.0f;

    for (int j = 0; j < 64; j += 4) {
        const float4 h0 = *(const float4*)&HSB(tb + 0, j);
        const float4 h1 = *(const float4*)&HSB(tb + 1, j);
        const float4 h2 = *(const float4*)&HSB(tb + 2, j);
        const float4 h3 = *(const float4*)&HSB(tb + 3, j);
        const float hv[4][4] = {{h0.x,h0.y,h0.z,h0.w},{h1.x,h1.y,h1.z,h1.w},
                                {h2.x,h2.y,h2.z,h2.w},{h3.x,h3.y,h3.z,h3.w}};
        #pragma unroll
        for (int jj = 0; jj < 4; ++jj) {
            const float4 wA = *(const float4*)&WcF(j + jj, c0);
            const float4 wB = *(const float4*)&WcF(j + jj, 64 + c0);
            const float wv8[8] = {wA.x,wA.y,wA.z,wA.w,wB.x,wB.y,wB.z,wB.w};
            #pragma unroll
            for (int i = 0; i < 4; ++i)
                #pragma unroll
                for (int q = 0; q < 8; ++q)
                    acc[i][q] = fmaf(hv[i][jj], wv8[q], acc[i][q]);
        }
    }

    // ---- epilogue: v -> global (one float4/token), off -> loc direct, attn -> LDS
    {
        const int n = c0 >> 5, cc = c0 & 31;
        const float4 bv4 = *(const float4*)&bv[c0];
        #pragma unroll
        for (int i = 0; i < 4; ++i) {
            const int pix = pix0 + tb + i;
            float4 o = {acc[i][0] + bv4.x, acc[i][1] + bv4.y,
                        acc[i][2] + bv4.z, acc[i][3] + bv4.w};
            *(float4*)&v_ws[((size_t)(b * 2 + n) * HWq + pix) * 32 + cc] = o;
        }
    }
    if (cg <= 8) {                        // off cols 64..99 -> loc = ref + off + boff
        const int co0 = c0;               // 0..32
        #pragma unroll
        for (int i = 0; i < 4; ++i) {
            const size_t tokg = (size_t)tok0 + tb + i;
            #pragma unroll
            for (int q = 0; q < 4; ++q) {
                const int co = co0 + q;
                const int rco = (co >= 18) ? co - 18 : co;
                loc_ws[tokg * 36 + co] = ref[tokg * 18 + rco] + acc[i][4 + q] + boff[co];
            }
        }
    } else if (cg <= 13) {                // attn logit cols 100..117
        #pragma unroll
        for (int q = 0; q < 4; ++q) {
            const int c = 64 + c0 + q;
            if (c < 118) {
                const float bav = ba[c - 100];
                #pragma unroll
                for (int i = 0; i < 4; ++i) LG(tb + i, c - 100) = acc[i][4 + q] + bav;
            }
        }
    }
    __syncthreads();

    // ---- softmax per (token, head)
    if (t < TOKA * 2) {
        const int tk = t >> 1, head = t & 1;
        float mx = -1e30f;
        #pragma unroll
        for (int k = 0; k < 9; ++k) mx = fmaxf(mx, LG(tk, head * 9 + k));
        float e[9], s = 0.0f;
        #pragma unroll
        for (int k = 0; k < 9; ++k) { e[k] = expf(LG(tk, head * 9 + k) - mx); s += e[k]; }
        const float inv = 1.0f / s;
        float* dst = &attn_ws[(size_t)(tok0 + tk) * 18 + head * 9];
        #pragma unroll
        for (int k = 0; k < 9; ++k) dst[k] = e[k] * inv;
    }
#undef WcF
#undef HSB
#undef LG
}

// ============ Kernel B: bilinear sample (split weight-prep / gather) + Wo ====
__global__ __launch_bounds__(256) void kB(
    const float* __restrict__ x, const float* __restrict__ v_ws,
    const float* __restrict__ loc_ws, const float* __restrict__ attn_ws,
    const float* __restrict__ Wo, const float* __restrict__ bo,
    float* __restrict__ out)
{
    __shared__ float wt4[TOKB * 18][4];
    __shared__ int   px4[TOKB * 18][4];
    __shared__ float sout[TOKB][68];
    const int t = threadIdx.x;
    // XCD-chunked swizzle: 2048 blocks, 8 XCDs, 256 contiguous blocks per XCD
    const int bid = (blockIdx.x & 7) * (NTOK / TOKB / 8) + (blockIdx.x >> 3);
    const int tok0 = bid * TOKB;
    const int b = tok0 >> 15;

    // ---- phase A: one lane per (token, head, k): weights+indices, attn folded
    for (int idx = t; idx < TOKB * 18; idx += 256) {
        const int tk = idx / 18, rem = idx - tk * 18;   // rem = head*9 + k
        const size_t tokg = (size_t)tok0 + tk;
        const float gx = loc_ws[tokg * 36 + rem * 2];
        const float gy = loc_ws[tokg * 36 + rem * 2 + 1];
        const float a  = attn_ws[tokg * 18 + rem];
        const float ix = fmaf(gx, 128.0f, 127.5f);
        const float iy = fmaf(gy, 64.0f, 63.5f);
        const float x0f = floorf(ix), y0f = floorf(iy);
        const float wx1 = ix - x0f, wy1 = iy - y0f;
        const float wx0 = 1.0f - wx1, wy0 = 1.0f - wy1;
        const int x0 = (int)x0f, y0 = (int)y0f;
        const int x1i = x0 + 1, y1i = y0 + 1;
        const int x0c = min(max(x0, 0), Wq - 1), y0c = min(max(y0, 0), Hq - 1);
        const int x1c = min(max(x1i, 0), Wq - 1), y1c = min(max(y1i, 0), Hq - 1);
        const bool vx0 = (x0 >= 0) & (x0 <= Wq - 1);
        const bool vy0 = (y0 >= 0) & (y0 <= Hq - 1);
        const bool vx1 = (x1i >= 0) & (x1i <= Wq - 1);
        const bool vy1 = (y1i >= 0) & (y1i <= Hq - 1);
        const float ax0 = a * wx0, ax1 = a * wx1;
        float4 w = {(vx0 && vy0) ? ax0 * wy0 : 0.0f,
                    (vx1 && vy0) ? ax1 * wy0 : 0.0f,
                    (vx0 && vy1) ? ax0 * wy1 : 0.0f,
                    (vx1 && vy1) ? ax1 * wy1 : 0.0f};
        int4 p = {(((y0c << 8) + x0c) << 5), (((y0c << 8) + x1c) << 5),
                  (((y1c << 8) + x0c) << 5), (((y1c << 8) + x1c) << 5)};
        *(float4*)wt4[idx] = w;
        *(int4*)px4[idx] = p;
    }
    __syncthreads();

    // ---- phase B: gathers only. wave handles 8 tokens, lane = (n, cc)
    const int lane = t & 63, wvid = t >> 6;
    const int n = lane >> 5, cc = lane & 31;
    const float* __restrict__ vimg = v_ws + (size_t)(b * 2 + n) * HWq * 32;
    for (int i = 0; i < 8; ++i) {
        const int tk = wvid * 8 + i;
        const int base = tk * 18 + n * 9;
        float accs = 0.0f;
        #pragma unroll
        for (int k = 0; k < 9; ++k) {
            const float4 w = *(const float4*)wt4[base + k];
            const int4  p = *(const int4*)px4[base + k];
            accs = fmaf(w.x, vimg[p.x + cc], accs);
            accs = fmaf(w.y, vimg[p.y + cc], accs);
            accs = fmaf(w.z, vimg[p.z + cc], accs);
            accs = fmaf(w.w, vimg[p.w + cc], accs);
        }
        sout[tk][lane] = accs;
    }
    __syncthreads();

    // ---- Wo GEMM: 2 tok x 4 col tile, Wo streamed through L1
    const int cg = t & 15, tg = t >> 4;
    const int cb = cg * 4, tb = tg * 2;
    float acc[2][4];
    #pragma unroll
    for (int i = 0; i < 2; ++i)
        #pragma unroll
        for (int q = 0; q < 4; ++q) acc[i][q] = 0.0f;

    for (int j = 0; j < 64; j += 4) {
        const float4 h0 = *(const float4*)&sout[tb + 0][j];
        const float4 h1 = *(const float4*)&sout[tb + 1][j];
        const float hv[2][4] = {{h0.x,h0.y,h0.z,h0.w},{h1.x,h1.y,h1.z,h1.w}};
        #pragma unroll
        for (int jj = 0; jj < 4; ++jj) {
            const float4 w = *(const float4*)&Wo[(size_t)(j + jj) * 64 + cb];
            const float wv4[4] = {w.x, w.y, w.z, w.w};
            #pragma unroll
            for (int i = 0; i < 2; ++i)
                #pragma unroll
                for (int q = 0; q < 4; ++q)
                    acc[i][q] = fmaf(hv[i][jj], wv4[q], acc[i][q]);
        }
    }
    const float4 bo4 = *(const float4*)&bo[cb];
    #pragma unroll
    for (int i = 0; i < 2; ++i) {
        const size_t tokg = (size_t)tok0 + tb + i;
        const float4 r = *(const float4*)&x[tokg * 64 + cb];
        float4 o = {acc[i][0]+bo4.x+r.x, acc[i][1]+bo4.y+r.y,
                    acc[i][2]+bo4.z+r.z, acc[i][3]+bo4.w+r.w};
        *(float4*)&out[tokg * 64 + cb] = o;
    }
}

// ============ Kernel C: LN2 + bf16 MFMA W1 + GELU -> y (bf16) ================
// 512 threads (8 waves), 64 tokens/block.
__global__ __launch_bounds__(512) void kC(
    const float* __restrict__ x1, const float* __restrict__ g2, const float* __restrict__ be2,
    const float* __restrict__ W1, const float* __restrict__ c1,
    unsigned short* __restrict__ y_ws)
{
    __shared__ unsigned short W1T[256 * 64];    // bf16 [col][k], swizzled (32 KB)
    __shared__ unsigned short hb2[TOKC * 64];   // bf16 [tok][k], swizzled (8 KB)
    __shared__ unsigned short ytile[TOKC * 256];// bf16 [tok][col], swizzled (32 KB)
    const int t = threadIdx.x;
    const int tok0 = blockIdx.x * TOKC;

    // ---- stage W1 -> bf16 transposed swizzled
    #pragma unroll 4
    for (int i = 0; i < 16; ++i) {
        const int p = t + i * 512;              // p < 8192
        const int c = p & 255, k2 = p >> 8;     // k = 2*k2
        const float w0 = W1[(size_t)(2 * k2) * 256 + c];
        const float w1 = W1[(size_t)(2 * k2 + 1) * 256 + c];
        const unsigned int pk = (unsigned int)f2bf(w0) | ((unsigned int)f2bf(w1) << 16);
        const unsigned int uidx = ((unsigned int)(c * 32 + k2)) ^ (((unsigned int)(c & 7)) << 2);
        ((unsigned int*)W1T)[uidx] = pk;
    }

    // ---- LN2: thread = (token, quarter), 2-step shuffle; write h as bf16
    if (t < TOKC * 4) {
        const int tok = t >> 2, part = t & 3;
        const int chb = part * 16;
        const float* xp = x1 + (size_t)(tok0 + tok) * 64 + chb;
        const float4 v0 = ((const float4*)xp)[0];
        const float4 v1 = ((const float4*)xp)[1];
        const float4 v2 = ((const float4*)xp)[2];
        const float4 v3 = ((const float4*)xp)[3];
        float s = ((v0.x + v0.y) + (v0.z + v0.w)) + ((v1.x + v1.y) + (v1.z + v1.w))
                + ((v2.x + v2.y) + (v2.z + v2.w)) + ((v3.x + v3.y) + (v3.z + v3.w));
        float s2 = 0.0f;
        s2 = fmaf(v0.x, v0.x, s2); s2 = fmaf(v0.y, v0.y, s2);
        s2 = fmaf(v0.z, v0.z, s2); s2 = fmaf(v0.w, v0.w, s2);
        s2 = fmaf(v1.x, v1.x, s2); s2 = fmaf(v1.y, v1.y, s2);
        s2 = fmaf(v1.z, v1.z, s2); s2 = fmaf(v1.w, v1.w, s2);
        s2 = fmaf(v2.x, v2.x, s2); s2 = fmaf(v2.y, v2.y, s2);
        s2 = fmaf(v2.z, v2.z, s2); s2 = fmaf(v2.w, v2.w, s2);
        s2 = fmaf(v3.x, v3.x, s2); s2 = fmaf(v3.y, v3.y, s2);
        s2 = fmaf(v3.z, v3.z, s2); s2 = fmaf(v3.w, v3.w, s2);
        s  += __shfl_xor(s, 1);  s2 += __shfl_xor(s2, 1);
        s  += __shfl_xor(s, 2);  s2 += __shfl_xor(s2, 2);
        const float m  = s * (1.0f / 64.0f);
        const float var = fmaf(-m, m, s2 * (1.0f / 64.0f));
        const float rs = rsqrtf(var + 1e-5f);
        const float nb = -m * rs;
        const float vv[16] = {v0.x,v0.y,v0.z,v0.w, v1.x,v1.y,v1.z,v1.w,
                              v2.x,v2.y,v2.z,v2.w, v3.x,v3.y,v3.z,v3.w};
        unsigned int pk[8];
        #pragma unroll
        for (int q = 0; q < 8; ++q) {
            const float hA = fmaf(fmaf(vv[2*q], rs, nb), g2[chb + 2*q], be2[chb + 2*q]);
            const float hB = fmaf(fmaf(vv[2*q+1], rs, nb), g2[chb + 2*q+1], be2[chb + 2*q+1]);
            pk[q] = (unsigned int)f2bf(hA) | ((unsigned int)f2bf(hB) << 16);
        }
        const unsigned int swz = ((unsigned int)(tok & 7)) << 3;
        unsigned int hi0 = ((unsigned int)(tok * 64 + chb)) ^ swz;
        unsigned int hi1 = ((unsigned int)(tok * 64 + chb + 8)) ^ swz;
        uint4 gA = {pk[0], pk[1], pk[2], pk[3]};
        uint4 gB = {pk[4], pk[5], pk[6], pk[7]};
        *(uint4*)&hb2[hi0] = gA;
        *(uint4*)&hb2[hi1] = gB;
    }
    __syncthreads();

    // ---- MFMA: wave w: M-tile (w&3), N-quad (w>>2). 16 mfma/wave.
    const int lane = t & 63, wv = t >> 6;
    const int mtile = wv & 3, nquad = wv >> 2;
    const int fr = lane & 15, kb = (lane >> 4) * 8;
    const int atok = mtile * 16 + fr;
    f32x4v acc[8];
    #pragma unroll
    for (int nt = 0; nt < 8; ++nt) acc[nt] = (f32x4v){0.0f, 0.0f, 0.0f, 0.0f};

    #pragma unroll
    for (int ks = 0; ks < 2; ++ks) {
        const short8v a = *(const short8v*)&hb2[(atok * 64 + ks * 32 + kb) ^ ((atok & 7) << 3)];
        #pragma unroll
        for (int nt = 0; nt < 8; ++nt) {
            const int col = nquad * 128 + nt * 16 + fr;
            const short8v bfr = *(const short8v*)&W1T[(col * 64 + ks * 32 + kb) ^ ((col & 7) << 3)];
            acc[nt] = __builtin_amdgcn_mfma_f32_16x16x32_bf16(a, bfr, acc[nt], 0, 0, 0);
        }
    }

    // ---- bias + GELU -> ytile (bf16, swizzled)
    #pragma unroll
    for (int nt = 0; nt < 8; ++nt) {
        const int col = nquad * 128 + nt * 16 + fr;
        const float c1v = c1[col];
        #pragma unroll
        for (int r = 0; r < 4; ++r) {
            const int tok = mtile * 16 + (lane >> 4) * 4 + r;
            const float val = gelu_exact(acc[nt][r] + c1v);
            ytile[((unsigned)(tok * 256 + col)) ^ (((unsigned)(tok & 7)) << 3)] = f2bf(val);
        }
    }
    __syncthreads();

    // ---- coalesced y write: thread t -> row t>>3, 32 ushorts
    {
        const int row = t >> 3, cb = (t & 7) * 32;
        const unsigned int swz = ((unsigned int)(row & 7)) << 3;
        unsigned short* dst = y_ws + (size_t)(tok0 + row) * 256 + cb;
        #pragma unroll
        for (int j = 0; j < 4; ++j) {
            const unsigned int hidx = ((unsigned int)(row * 256 + cb + j * 8)) ^ swz;
            *(uint4*)(dst + j * 8) = *(const uint4*)&ytile[hidx];
        }
    }
}

// ============ Kernel D: depthwise 3x3 + GELU + bf16 MFMA W2 + residual =======
__global__ __launch_bounds__(256) void kD(
    const unsigned short* __restrict__ y_ws, const float* __restrict__ Wdw, const float* __restrict__ bdw,
    const float* __restrict__ W2, const float* __restrict__ c2,
    float* __restrict__ out)
{
    __shared__ unsigned short W2T[64 * 256];    // bf16 [col][k], swizzled (32 KB)
    __shared__ unsigned short zsb2[PIXD * 256]; // bf16 [pix][k], swizzled (16 KB)
    const int t = threadIdx.x;
    const int bid = blockIdx.x;                 // 2 * 128 * 8 = 2048 blocks
    const int b = bid >> 10;                    // 1024 per batch
    const int rem = bid & 1023;
    const int hh = rem >> 3;                    // 8 strips per row
    const int ww0 = (rem & 7) * PIXD;

    // stage W2 -> bf16, transposed, swizzled
    #pragma unroll 4
    for (int i = 0; i < 32; ++i) {
        const int p = t + i * 256;             // p < 8192
        const int c = p & 63, k2 = p >> 6;     // k = 2*k2
        const float w0 = W2[(size_t)(2 * k2) * 64 + c];
        const float w1 = W2[(size_t)(2 * k2 + 1) * 64 + c];
        const unsigned int pk = (unsigned int)f2bf(w0) | ((unsigned int)f2bf(w1) << 16);
        const unsigned int uidx = ((unsigned int)(c * 128 + k2)) ^ (((unsigned int)(c & 7)) << 2);
        ((unsigned int*)W2T)[uidx] = pk;
    }

    // phase 1: depthwise conv, thread = channel, slide over PIXD pixels
    {
        const unsigned short* __restrict__ yb = y_ws + (size_t)b * HWq * 256;
        float wd[9];
        #pragma unroll
        for (int q = 0; q < 9; ++q) wd[q] = Wdw[t * 9 + q];
        const float bdv = bdw[t];
        const bool r0ok = (hh > 0), r2ok = (hh < Hq - 1);
        const int y0r = (hh - 1) << 8, y1r = hh << 8, y2r = (hh + 1) << 8;

        float u0[3], u1[3], u2[3];
        {
            const int xm = (ww0 - 1) & 255, xc = ww0;
            u0[0] = r0ok ? bf2f(yb[(size_t)(y0r + xm) * 256 + t]) : 0.0f;
            u0[1] =        bf2f(yb[(size_t)(y1r + xm) * 256 + t]);
            u0[2] = r2ok ? bf2f(yb[(size_t)(y2r + xm) * 256 + t]) : 0.0f;
            u1[0] = r0ok ? bf2f(yb[(size_t)(y0r + xc) * 256 + t]) : 0.0f;
            u1[1] =        bf2f(yb[(size_t)(y1r + xc) * 256 + t]);
            u1[2] = r2ok ? bf2f(yb[(size_t)(y2r + xc) * 256 + t]) : 0.0f;
        }
        #pragma unroll 4
        for (int p = 0; p < PIXD; ++p) {
            const int xp = (ww0 + p + 1) & 255;
            u2[0] = r0ok ? bf2f(yb[(size_t)(y0r + xp) * 256 + t]) : 0.0f;
            u2[1] =        bf2f(yb[(size_t)(y1r + xp) * 256 + t]);
            u2[2] = r2ok ? bf2f(yb[(size_t)(y2r + xp) * 256 + t]) : 0.0f;
            float a = bdv;
            a = fmaf(wd[0], u0[0], a); a = fmaf(wd[1], u1[0], a); a = fmaf(wd[2], u2[0], a);
            a = fmaf(wd[3], u0[1], a); a = fmaf(wd[4], u1[1], a); a = fmaf(wd[5], u2[1], a);
            a = fmaf(wd[6], u0[2], a); a = fmaf(wd[7], u1[2], a); a = fmaf(wd[8], u2[2], a);
            zsb2[(p * 256 + t) ^ ((p & 7) << 3)] = f2bf(gelu_exact(a));
            u0[0] = u1[0]; u0[1] = u1[1]; u0[2] = u1[2];
            u1[0] = u2[0]; u1[1] = u2[1]; u1[2] = u2[2];
        }
    }
    __syncthreads();

    // phase 2: z(32x256) @ W2(256x64) via mfma_f32_16x16x32_bf16.
    // wave wv owns 16 output cols; 2 M-tiles of 16 pixels.
    const int lane = t & 63, wv = t >> 6;
    const int fr = lane & 15;
    const int kb = (lane >> 4) * 8;
    const int col = wv * 16 + fr;
    f32x4v acc0 = {0.0f, 0.0f, 0.0f, 0.0f};
    f32x4v acc1 = {0.0f, 0.0f, 0.0f, 0.0f};
    #pragma unroll
    for (int kk = 0; kk < 8; ++kk) {
        const int ka = kk * 32 + kb;
        const short8v bfr = *(const short8v*)&W2T[(col * 256 + ka) ^ ((col & 7) << 3)];
        const short8v a0 = *(const short8v*)&zsb2[(fr * 256 + ka) ^ ((fr & 7) << 3)];
        const short8v a1 = *(const short8v*)&zsb2[((fr + 16) * 256 + ka) ^ ((fr & 7) << 3)];
        acc0 = __builtin_amdgcn_mfma_f32_16x16x32_bf16(a0, bfr, acc0, 0, 0, 0);
        acc1 = __builtin_amdgcn_mfma_f32_16x16x32_bf16(a1, bfr, acc1, 0, 0, 0);
    }
    const float c2v = c2[col];
    #pragma unroll
    for (int r = 0; r < 4; ++r) {
        const int prow = (lane >> 4) * 4 + r;
        const size_t tok0g = (size_t)b * HWq + ((size_t)hh << 8) + ww0;
        out[(tok0g + prow) * 64 + col] += acc0[r] + c2v;
        out[(tok0g + 16 + prow) * 64 + col] += acc1[r] + c2v;
    }
}

extern "C" void kernel_launch(void* const* d_in, const int* in_sizes, int n_in,
                              void* d_out, int out_size, void* d_ws, size_t ws_size,
                              hipStream_t stream) {
    const float* x    = (const float*)d_in[0];
    const float* ref  = (const float*)d_in[1];
    const float* g1   = (const float*)d_in[2];
    const float* be1  = (const float*)d_in[3];
    const float* g2   = (const float*)d_in[4];
    const float* be2  = (const float*)d_in[5];
    const float* Woff = (const float*)d_in[6];
    const float* boff = (const float*)d_in[7];
    const float* Wa   = (const float*)d_in[8];
    const float* ba   = (const float*)d_in[9];
    const float* Wv   = (const float*)d_in[10];
    const float* bv   = (const float*)d_in[11];
    const float* Wo   = (const float*)d_in[12];
    const float* bo   = (const float*)d_in[13];
    const float* W1   = (const float*)d_in[14];
    const float* c1   = (const float*)d_in[15];
    const float* Wdw  = (const float*)d_in[16];
    const float* bdw  = (const float*)d_in[17];
    const float* W2   = (const float*)d_in[18];
    const float* c2   = (const float*)d_in[19];

    float* out = (float*)d_out;
    float* ws = (float*)d_ws;
    float* v_ws    = ws;                                   // B*2*HW*32 floats
    float* loc_ws  = v_ws  + (size_t)Bq * 2 * HWq * 32;    // NTOK*36 floats
    float* attn_ws = loc_ws + (size_t)NTOK * 36;           // NTOK*18 floats
    unsigned short* y_ws = (unsigned short*)(attn_ws + (size_t)NTOK * 18); // NTOK*256 bf16

    hipLaunchKernelGGL(kA, dim3(NTOK / TOKA), dim3(512), 0, stream,
                       x, ref, g1, be1, Woff, boff, Wa, ba, Wv, bv,
                       v_ws, loc_ws, attn_ws);
    hipLaunchKernelGGL(kB, dim3(NTOK / TOKB), dim3(256), 0, stream,
                       x, v_ws, loc_ws, attn_ws, Wo, bo, out);
    hipLaunchKernelGGL(kC, dim3(NTOK / TOKC), dim3(512), 0, stream,
                       out, g2, be2, W1, c1, y_ws);
    hipLaunchKernelGGL(kD, dim3(Bq * Hq * (Wq / PIXD)), dim3(256), 0, stream,
                       y_ws, Wdw, bdw, W2, c2, out);
}

// Round 7
// 154.090 us; speedup vs baseline: 3.6007x; 1.1790x over previous
//
#include <hip/hip_runtime.h>
#include <math.h>

#define Bq 2
#define Hq 128
#define Wq 256
#define Cq 64
#define HIDq 256
#define HWq (Hq * Wq)
#define NTOK (Bq * HWq)

#define TOKA 128
#define TOKB 16
#define TOKC 64
#define PIXD 32

typedef __attribute__((ext_vector_type(8))) short short8v;
typedef __attribute__((ext_vector_type(4))) float f32x4v;
typedef __attribute__((ext_vector_type(4))) unsigned short ushort4v;

__device__ inline float gelu_exact(float x) {
    return 0.5f * x * (1.0f + erff(x * 0.70710678118654752440f));
}

__device__ inline unsigned short f2bf(float f) {
    unsigned int u = __float_as_uint(f);
    u += 0x7FFFu + ((u >> 16) & 1u);
    return (unsigned short)(u >> 16);
}

__device__ inline float bf2f(unsigned short u) {
    return __uint_as_float(((unsigned int)u) << 16);
}

// ============ Kernel A: LN1 + fused {Wv | Woff | Wa} GEMM, softmax, loc ======
// 512 threads, 128 tokens/block. Flat LDS: Wc[64][120] | hsb[128][68] | logit[128][20]
__global__ __launch_bounds__(512, 4) void kA(
    const float* __restrict__ x, const float* __restrict__ ref,
    const float* __restrict__ g1, const float* __restrict__ be1,
    const float* __restrict__ Woff, const float* __restrict__ boff,
    const float* __restrict__ Wa, const float* __restrict__ ba,
    const float* __restrict__ Wv, const float* __restrict__ bv,
    unsigned short* __restrict__ v16, float* __restrict__ loc_ws, float* __restrict__ attn_ws)
{
    __shared__ float lds[64 * 120 + TOKA * 68 + TOKA * 20];
#define WcF(j, c)   lds[(j) * 120 + (c)]
#define HSB(tk, ch) lds[7680 + (tk) * 68 + (ch)]
#define LG(tk, kk)  lds[7680 + TOKA * 68 + (tk) * 20 + (kk)]
    const int t = threadIdx.x;
    const int tok0 = blockIdx.x * TOKA;
    const int b = tok0 >> 15;          // HW = 32768
    const int pix0 = tok0 & (HWq - 1);

    // ---- stage fused weight matrix (cols: 0..63 Wv, 64..99 Woff, 100..117 Wa)
    for (int idx = t; idx < 64 * 120; idx += 512) {
        const int j = idx / 120, c = idx - j * 120;
        float w = 0.0f;
        if (c < 64) w = Wv[j * 64 + c];
        else if (c < 100) w = Woff[j * 36 + (c - 64)];
        else if (c < 118) w = Wa[j * 18 + (c - 100)];
        WcF(j, c) = w;
    }

    // ---- LayerNorm: thread = (token, quarter). Coalesced loads, 2-step shuffle.
    {
        const int tok = t >> 2, part = t & 3;
        const int chb = part * 16;
        const float* xp = x + (size_t)(tok0 + tok) * 64 + chb;
        const float4 v0 = ((const float4*)xp)[0];
        const float4 v1 = ((const float4*)xp)[1];
        const float4 v2 = ((const float4*)xp)[2];
        const float4 v3 = ((const float4*)xp)[3];
        float s = ((v0.x + v0.y) + (v0.z + v0.w)) + ((v1.x + v1.y) + (v1.z + v1.w))
                + ((v2.x + v2.y) + (v2.z + v2.w)) + ((v3.x + v3.y) + (v3.z + v3.w));
        float s2 = 0.0f;
        s2 = fmaf(v0.x, v0.x, s2); s2 = fmaf(v0.y, v0.y, s2);
        s2 = fmaf(v0.z, v0.z, s2); s2 = fmaf(v0.w, v0.w, s2);
        s2 = fmaf(v1.x, v1.x, s2); s2 = fmaf(v1.y, v1.y, s2);
        s2 = fmaf(v1.z, v1.z, s2); s2 = fmaf(v1.w, v1.w, s2);
        s2 = fmaf(v2.x, v2.x, s2); s2 = fmaf(v2.y, v2.y, s2);
        s2 = fmaf(v2.z, v2.z, s2); s2 = fmaf(v2.w, v2.w, s2);
        s2 = fmaf(v3.x, v3.x, s2); s2 = fmaf(v3.y, v3.y, s2);
        s2 = fmaf(v3.z, v3.z, s2); s2 = fmaf(v3.w, v3.w, s2);
        s  += __shfl_xor(s, 1);  s2 += __shfl_xor(s2, 1);
        s  += __shfl_xor(s, 2);  s2 += __shfl_xor(s2, 2);
        const float m  = s * (1.0f / 64.0f);
        const float var = fmaf(-m, m, s2 * (1.0f / 64.0f));
        const float rs = rsqrtf(var + 1e-5f);
        const float nb = -m * rs;
        const float4 gA = *(const float4*)(g1 + chb),     gB = *(const float4*)(g1 + chb + 4);
        const float4 gC = *(const float4*)(g1 + chb + 8), gD = *(const float4*)(g1 + chb + 12);
        const float4 bA = *(const float4*)(be1 + chb),     bB = *(const float4*)(be1 + chb + 4);
        const float4 bC = *(const float4*)(be1 + chb + 8), bD = *(const float4*)(be1 + chb + 12);
        float4* hrow = (float4*)&HSB(tok, chb);
        float4 h0 = {fmaf(fmaf(v0.x, rs, nb), gA.x, bA.x), fmaf(fmaf(v0.y, rs, nb), gA.y, bA.y),
                     fmaf(fmaf(v0.z, rs, nb), gA.z, bA.z), fmaf(fmaf(v0.w, rs, nb), gA.w, bA.w)};
        float4 h1 = {fmaf(fmaf(v1.x, rs, nb), gB.x, bB.x), fmaf(fmaf(v1.y, rs, nb), gB.y, bB.y),
                     fmaf(fmaf(v1.z, rs, nb), gB.z, bB.z), fmaf(fmaf(v1.w, rs, nb), gB.w, bB.w)};
        float4 h2 = {fmaf(fmaf(v2.x, rs, nb), gC.x, bC.x), fmaf(fmaf(v2.y, rs, nb), gC.y, bC.y),
                     fmaf(fmaf(v2.z, rs, nb), gC.z, bC.z), fmaf(fmaf(v2.w, rs, nb), gC.w, bC.w)};
        float4 h3 = {fmaf(fmaf(v3.x, rs, nb), gD.x, bD.x), fmaf(fmaf(v3.y, rs, nb), gD.y, bD.y),
                     fmaf(fmaf(v3.z, rs, nb), gD.z, bD.z), fmaf(fmaf(v3.w, rs, nb), gD.w, bD.w)};
        hrow[0] = h0; hrow[1] = h1; hrow[2] = h2; hrow[3] = h3;
    }
    __syncthreads();

    // ---- GEMM: 32 token-groups x 16 col-groups; lane owns cols {cg*4..+3, 64+cg*4..+3}
    const int cg = t & 15, tg = t >> 4;
    const int tb = tg * 4;
    const int c0 = cg * 4;
    float acc[4][8];
    #pragma unroll
    for (int i = 0; i < 4; ++i)
        #pragma unroll
        for (int q = 0; q < 8; ++q) acc[i][q] = 0.0f;

    for (int j = 0; j < 64; j += 4) {
        const float4 h0 = *(const float4*)&HSB(tb + 0, j);
        const float4 h1 = *(const float4*)&HSB(tb + 1, j);
        const float4 h2 = *(const float4*)&HSB(tb + 2, j);
        const float4 h3 = *(const float4*)&HSB(tb + 3, j);
        const float hv[4][4] = {{h0.x,h0.y,h0.z,h0.w},{h1.x,h1.y,h1.z,h1.w},
                                {h2.x,h2.y,h2.z,h2.w},{h3.x,h3.y,h3.z,h3.w}};
        #pragma unroll
        for (int jj = 0; jj < 4; ++jj) {
            const float4 wA = *(const float4*)&WcF(j + jj, c0);
            const float4 wB = *(const float4*)&WcF(j + jj, 64 + c0);
            const float wv8[8] = {wA.x,wA.y,wA.z,wA.w,wB.x,wB.y,wB.z,wB.w};
            #pragma unroll
            for (int i = 0; i < 4; ++i)
                #pragma unroll
                for (int q = 0; q < 8; ++q)
                    acc[i][q] = fmaf(hv[i][jj], wv8[q], acc[i][q]);
        }
    }

    // ---- epilogue: v -> global bf16 (ushort4/token), off -> loc direct, attn -> LDS
    {
        const int n = c0 >> 5, cc = c0 & 31;
        const float4 bv4 = *(const float4*)&bv[c0];
        #pragma unroll
        for (int i = 0; i < 4; ++i) {
            const int pix = pix0 + tb + i;
            ushort4v o = {f2bf(acc[i][0] + bv4.x), f2bf(acc[i][1] + bv4.y),
                          f2bf(acc[i][2] + bv4.z), f2bf(acc[i][3] + bv4.w)};
            *(ushort4v*)&v16[((size_t)(b * 2 + n) * HWq + pix) * 32 + cc] = o;
        }
    }
    if (cg <= 8) {                        // off cols 64..99 -> loc = ref + off + boff
        const int co0 = c0;               // 0..32
        #pragma unroll
        for (int i = 0; i < 4; ++i) {
            const size_t tokg = (size_t)tok0 + tb + i;
            #pragma unroll
            for (int q = 0; q < 4; ++q) {
                const int co = co0 + q;
                const int rco = (co >= 18) ? co - 18 : co;
                loc_ws[tokg * 36 + co] = ref[tokg * 18 + rco] + acc[i][4 + q] + boff[co];
            }
        }
    } else if (cg <= 13) {                // attn logit cols 100..117
        #pragma unroll
        for (int q = 0; q < 4; ++q) {
            const int c = 64 + c0 + q;
            if (c < 118) {
                const float bav = ba[c - 100];
                #pragma unroll
                for (int i = 0; i < 4; ++i) LG(tb + i, c - 100) = acc[i][4 + q] + bav;
            }
        }
    }
    __syncthreads();

    // ---- softmax per (token, head)
    if (t < TOKA * 2) {
        const int tk = t >> 1, head = t & 1;
        float mx = -1e30f;
        #pragma unroll
        for (int k = 0; k < 9; ++k) mx = fmaxf(mx, LG(tk, head * 9 + k));
        float e[9], s = 0.0f;
        #pragma unroll
        for (int k = 0; k < 9; ++k) { e[k] = expf(LG(tk, head * 9 + k) - mx); s += e[k]; }
        const float inv = 1.0f / s;
        float* dst = &attn_ws[(size_t)(tok0 + tk) * 18 + head * 9];
        #pragma unroll
        for (int k = 0; k < 9; ++k) dst[k] = e[k] * inv;
    }
#undef WcF
#undef HSB
#undef LG
}

// ============ Kernel B: bilinear sample (bf16 v) + Wo + residual =============
__global__ __launch_bounds__(256) void kB(
    const float* __restrict__ x, const unsigned short* __restrict__ v16,
    const float* __restrict__ loc_ws, const float* __restrict__ attn_ws,
    const float* __restrict__ Wo, const float* __restrict__ bo,
    float* __restrict__ out)
{
    __shared__ float wt4[TOKB * 18][4];
    __shared__ int   px4[TOKB * 18][4];
    __shared__ float sout[TOKB][68];
    const int t = threadIdx.x;
    // XCD-chunked swizzle: 4096 blocks, 8 XCDs, 512 contiguous per XCD
    const int bid = (blockIdx.x & 7) * (NTOK / TOKB / 8) + (blockIdx.x >> 3);
    const int tok0 = bid * TOKB;
    const int b = tok0 >> 15;

    // ---- phase A: one lane per (token, head, k): weights+indices, attn folded
    for (int idx = t; idx < TOKB * 18; idx += 256) {
        const int tk = idx / 18, rem = idx - tk * 18;   // rem = head*9 + k
        const size_t tokg = (size_t)tok0 + tk;
        const float gx = loc_ws[tokg * 36 + rem * 2];
        const float gy = loc_ws[tokg * 36 + rem * 2 + 1];
        const float a  = attn_ws[tokg * 18 + rem];
        const float ix = fmaf(gx, 128.0f, 127.5f);
        const float iy = fmaf(gy, 64.0f, 63.5f);
        const float x0f = floorf(ix), y0f = floorf(iy);
        const float wx1 = ix - x0f, wy1 = iy - y0f;
        const float wx0 = 1.0f - wx1, wy0 = 1.0f - wy1;
        const int x0 = (int)x0f, y0 = (int)y0f;
        const int x1i = x0 + 1, y1i = y0 + 1;
        const int x0c = min(max(x0, 0), Wq - 1), y0c = min(max(y0, 0), Hq - 1);
        const int x1c = min(max(x1i, 0), Wq - 1), y1c = min(max(y1i, 0), Hq - 1);
        const bool vx0 = (x0 >= 0) & (x0 <= Wq - 1);
        const bool vy0 = (y0 >= 0) & (y0 <= Hq - 1);
        const bool vx1 = (x1i >= 0) & (x1i <= Wq - 1);
        const bool vy1 = (y1i >= 0) & (y1i <= Hq - 1);
        const float ax0 = a * wx0, ax1 = a * wx1;
        float4 w = {(vx0 && vy0) ? ax0 * wy0 : 0.0f,
                    (vx1 && vy0) ? ax1 * wy0 : 0.0f,
                    (vx0 && vy1) ? ax0 * wy1 : 0.0f,
                    (vx1 && vy1) ? ax1 * wy1 : 0.0f};
        int4 p = {(((y0c << 8) + x0c) << 5), (((y0c << 8) + x1c) << 5),
                  (((y1c << 8) + x0c) << 5), (((y1c << 8) + x1c) << 5)};
        *(float4*)wt4[idx] = w;
        *(int4*)px4[idx] = p;
    }
    __syncthreads();

    // ---- phase B: gathers only. wave handles 4 tokens, lane = (n, cc)
    const int lane = t & 63, wvid = t >> 6;
    const int n = lane >> 5, cc = lane & 31;
    const unsigned short* __restrict__ vimg = v16 + (size_t)(b * 2 + n) * HWq * 32;
    for (int i = 0; i < 4; ++i) {
        const int tk = wvid * 4 + i;
        const int base = tk * 18 + n * 9;
        float accs = 0.0f;
        #pragma unroll
        for (int k = 0; k < 9; ++k) {
            const float4 w = *(const float4*)wt4[base + k];
            const int4  p = *(const int4*)px4[base + k];
            accs = fmaf(w.x, bf2f(vimg[p.x + cc]), accs);
            accs = fmaf(w.y, bf2f(vimg[p.y + cc]), accs);
            accs = fmaf(w.z, bf2f(vimg[p.z + cc]), accs);
            accs = fmaf(w.w, bf2f(vimg[p.w + cc]), accs);
        }
        sout[tk][lane] = accs;
    }
    __syncthreads();

    // ---- Wo GEMM: 1 tok x 4 col per thread, Wo streamed through L1
    const int cg = t & 15, tg = t >> 4;
    const int cb = cg * 4;
    float acc4[4] = {0.0f, 0.0f, 0.0f, 0.0f};
    for (int j = 0; j < 64; j += 4) {
        const float4 h = *(const float4*)&sout[tg][j];
        const float hv[4] = {h.x, h.y, h.z, h.w};
        #pragma unroll
        for (int jj = 0; jj < 4; ++jj) {
            const float4 w = *(const float4*)&Wo[(size_t)(j + jj) * 64 + cb];
            acc4[0] = fmaf(hv[jj], w.x, acc4[0]);
            acc4[1] = fmaf(hv[jj], w.y, acc4[1]);
            acc4[2] = fmaf(hv[jj], w.z, acc4[2]);
            acc4[3] = fmaf(hv[jj], w.w, acc4[3]);
        }
    }
    const float4 bo4 = *(const float4*)&bo[cb];
    const size_t tokg = (size_t)tok0 + tg;
    const float4 r = *(const float4*)&x[tokg * 64 + cb];
    float4 o = {acc4[0]+bo4.x+r.x, acc4[1]+bo4.y+r.y, acc4[2]+bo4.z+r.z, acc4[3]+bo4.w+r.w};
    *(float4*)&out[tokg * 64 + cb] = o;
}

// ============ Kernel C: LN2 + bf16 MFMA W1 + GELU -> y (bf16) ================
// 512 threads (8 waves), 64 tokens/block.
__global__ __launch_bounds__(512) void kC(
    const float* __restrict__ x1, const float* __restrict__ g2, const float* __restrict__ be2,
    const float* __restrict__ W1, const float* __restrict__ c1,
    unsigned short* __restrict__ y_ws)
{
    __shared__ unsigned short W1T[256 * 64];    // bf16 [col][k], swizzled (32 KB)
    __shared__ unsigned short hb2[TOKC * 64];   // bf16 [tok][k], swizzled (8 KB)
    __shared__ unsigned short ytile[TOKC * 256];// bf16 [tok][col], swizzled (32 KB)
    const int t = threadIdx.x;
    const int tok0 = blockIdx.x * TOKC;

    // ---- stage W1 -> bf16 transposed swizzled
    #pragma unroll 4
    for (int i = 0; i < 16; ++i) {
        const int p = t + i * 512;              // p < 8192
        const int c = p & 255, k2 = p >> 8;     // k = 2*k2
        const float w0 = W1[(size_t)(2 * k2) * 256 + c];
        const float w1 = W1[(size_t)(2 * k2 + 1) * 256 + c];
        const unsigned int pk = (unsigned int)f2bf(w0) | ((unsigned int)f2bf(w1) << 16);
        const unsigned int uidx = ((unsigned int)(c * 32 + k2)) ^ (((unsigned int)(c & 7)) << 2);
        ((unsigned int*)W1T)[uidx] = pk;
    }

    // ---- LN2: thread = (token, quarter), 2-step shuffle; write h as bf16
    if (t < TOKC * 4) {
        const int tok = t >> 2, part = t & 3;
        const int chb = part * 16;
        const float* xp = x1 + (size_t)(tok0 + tok) * 64 + chb;
        const float4 v0 = ((const float4*)xp)[0];
        const float4 v1 = ((const float4*)xp)[1];
        const float4 v2 = ((const float4*)xp)[2];
        const float4 v3 = ((const float4*)xp)[3];
        float s = ((v0.x + v0.y) + (v0.z + v0.w)) + ((v1.x + v1.y) + (v1.z + v1.w))
                + ((v2.x + v2.y) + (v2.z + v2.w)) + ((v3.x + v3.y) + (v3.z + v3.w));
        float s2 = 0.0f;
        s2 = fmaf(v0.x, v0.x, s2); s2 = fmaf(v0.y, v0.y, s2);
        s2 = fmaf(v0.z, v0.z, s2); s2 = fmaf(v0.w, v0.w, s2);
        s2 = fmaf(v1.x, v1.x, s2); s2 = fmaf(v1.y, v1.y, s2);
        s2 = fmaf(v1.z, v1.z, s2); s2 = fmaf(v1.w, v1.w, s2);
        s2 = fmaf(v2.x, v2.x, s2); s2 = fmaf(v2.y, v2.y, s2);
        s2 = fmaf(v2.z, v2.z, s2); s2 = fmaf(v2.w, v2.w, s2);
        s2 = fmaf(v3.x, v3.x, s2); s2 = fmaf(v3.y, v3.y, s2);
        s2 = fmaf(v3.z, v3.z, s2); s2 = fmaf(v3.w, v3.w, s2);
        s  += __shfl_xor(s, 1);  s2 += __shfl_xor(s2, 1);
        s  += __shfl_xor(s, 2);  s2 += __shfl_xor(s2, 2);
        const float m  = s * (1.0f / 64.0f);
        const float var = fmaf(-m, m, s2 * (1.0f / 64.0f));
        const float rs = rsqrtf(var + 1e-5f);
        const float nb = -m * rs;
        const float vv[16] = {v0.x,v0.y,v0.z,v0.w, v1.x,v1.y,v1.z,v1.w,
                              v2.x,v2.y,v2.z,v2.w, v3.x,v3.y,v3.z,v3.w};
        unsigned int pk[8];
        #pragma unroll
        for (int q = 0; q < 8; ++q) {
            const float hA = fmaf(fmaf(vv[2*q], rs, nb), g2[chb + 2*q], be2[chb + 2*q]);
            const float hB = fmaf(fmaf(vv[2*q+1], rs, nb), g2[chb + 2*q+1], be2[chb + 2*q+1]);
            pk[q] = (unsigned int)f2bf(hA) | ((unsigned int)f2bf(hB) << 16);
        }
        const unsigned int swz = ((unsigned int)(tok & 7)) << 3;
        unsigned int hi0 = ((unsigned int)(tok * 64 + chb)) ^ swz;
        unsigned int hi1 = ((unsigned int)(tok * 64 + chb + 8)) ^ swz;
        uint4 gA = {pk[0], pk[1], pk[2], pk[3]};
        uint4 gB = {pk[4], pk[5], pk[6], pk[7]};
        *(uint4*)&hb2[hi0] = gA;
        *(uint4*)&hb2[hi1] = gB;
    }
    __syncthreads();

    // ---- MFMA: wave w: M-tile (w&3), N-quad (w>>2). 16 mfma/wave.
    const int lane = t & 63, wv = t >> 6;
    const int mtile = wv & 3, nquad = wv >> 2;
    const int fr = lane & 15, kb = (lane >> 4) * 8;
    const int atok = mtile * 16 + fr;
    f32x4v acc[8];
    #pragma unroll
    for (int nt = 0; nt < 8; ++nt) acc[nt] = (f32x4v){0.0f, 0.0f, 0.0f, 0.0f};

    #pragma unroll
    for (int ks = 0; ks < 2; ++ks) {
        const short8v a = *(const short8v*)&hb2[(atok * 64 + ks * 32 + kb) ^ ((atok & 7) << 3)];
        #pragma unroll
        for (int nt = 0; nt < 8; ++nt) {
            const int col = nquad * 128 + nt * 16 + fr;
            const short8v bfr = *(const short8v*)&W1T[(col * 64 + ks * 32 + kb) ^ ((col & 7) << 3)];
            acc[nt] = __builtin_amdgcn_mfma_f32_16x16x32_bf16(a, bfr, acc[nt], 0, 0, 0);
        }
    }

    // ---- bias + GELU -> ytile (bf16, swizzled)
    #pragma unroll
    for (int nt = 0; nt < 8; ++nt) {
        const int col = nquad * 128 + nt * 16 + fr;
        const float c1v = c1[col];
        #pragma unroll
        for (int r = 0; r < 4; ++r) {
            const int tok = mtile * 16 + (lane >> 4) * 4 + r;
            const float val = gelu_exact(acc[nt][r] + c1v);
            ytile[((unsigned)(tok * 256 + col)) ^ (((unsigned)(tok & 7)) << 3)] = f2bf(val);
        }
    }
    __syncthreads();

    // ---- coalesced y write: thread t -> row t>>3, 32 ushorts
    {
        const int row = t >> 3, cb = (t & 7) * 32;
        const unsigned int swz = ((unsigned int)(row & 7)) << 3;
        unsigned short* dst = y_ws + (size_t)(tok0 + row) * 256 + cb;
        #pragma unroll
        for (int j = 0; j < 4; ++j) {
            const unsigned int hidx = ((unsigned int)(row * 256 + cb + j * 8)) ^ swz;
            *(uint4*)(dst + j * 8) = *(const uint4*)&ytile[hidx];
        }
    }
}

// ============ Kernel D: depthwise 3x3 (vectorized) + GELU + MFMA W2 ==========
// 256 threads: lane = channel-quad (4 ch), t>>6 = pixel sub-strip of 8.
__global__ __launch_bounds__(256) void kD(
    const unsigned short* __restrict__ y_ws, const float* __restrict__ Wdw, const float* __restrict__ bdw,
    const float* __restrict__ W2, const float* __restrict__ c2,
    float* __restrict__ out)
{
    __shared__ unsigned short W2T[64 * 256];    // bf16 [col][k], swizzled (32 KB)
    __shared__ unsigned short zsb2[PIXD * 256]; // bf16 [pix][k], swizzled (16 KB)
    const int t = threadIdx.x;
    // XCD-chunked swizzle: 2048 blocks, 256 contiguous per XCD (row locality in L2)
    const int bid = (blockIdx.x & 7) * 256 + (blockIdx.x >> 3);
    const int b = bid >> 10;                    // 1024 per batch
    const int rem = bid & 1023;
    const int hh = rem >> 3;                    // 8 strips per row
    const int ww0 = (rem & 7) * PIXD;

    // stage W2 -> bf16, transposed, swizzled
    #pragma unroll 4
    for (int i = 0; i < 32; ++i) {
        const int p = t + i * 256;             // p < 8192
        const int c = p & 63, k2 = p >> 6;     // k = 2*k2
        const float w0 = W2[(size_t)(2 * k2) * 64 + c];
        const float w1 = W2[(size_t)(2 * k2 + 1) * 64 + c];
        const unsigned int pk = (unsigned int)f2bf(w0) | ((unsigned int)f2bf(w1) << 16);
        const unsigned int uidx = ((unsigned int)(c * 128 + k2)) ^ (((unsigned int)(c & 7)) << 2);
        ((unsigned int*)W2T)[uidx] = pk;
    }

    // phase 1: depthwise conv. Thread = 4 channels x 8-pixel sub-strip.
    {
        const int lane = t & 63, sub = t >> 6;
        const int c4 = lane * 4;
        const int px0 = ww0 + sub * 8;
        const unsigned short* __restrict__ yb = y_ws + (size_t)b * HWq * 256;
        const bool r0ok = (hh > 0), r2ok = (hh < Hq - 1);
        const int y0r = (hh - 1) << 8, y1r = hh << 8, y2r = (hh + 1) << 8;

        float wd[9][4], bdv[4];
        #pragma unroll
        for (int j = 0; j < 4; ++j) {
            bdv[j] = bdw[c4 + j];
            #pragma unroll
            for (int q = 0; q < 9; ++q) wd[q][j] = Wdw[(c4 + j) * 9 + q];
        }

        float um1[3][4], uz0[3][4], up1[3][4];
        // load col helper inline: rows hh-1, hh, hh+1 at column xx
        #define LOADCOL(dst, xx) do {                                              \
            ushort4v v0q = r0ok ? *(const ushort4v*)&yb[((size_t)(y0r + (xx)) << 8) + c4] : (ushort4v){0,0,0,0}; \
            ushort4v v1q =        *(const ushort4v*)&yb[((size_t)(y1r + (xx)) << 8) + c4]; \
            ushort4v v2q = r2ok ? *(const ushort4v*)&yb[((size_t)(y2r + (xx)) << 8) + c4] : (ushort4v){0,0,0,0}; \
            _Pragma("unroll")                                                      \
            for (int j = 0; j < 4; ++j) {                                          \
                dst[0][j] = bf2f(v0q[j]); dst[1][j] = bf2f(v1q[j]); dst[2][j] = bf2f(v2q[j]); \
            } } while (0)

        LOADCOL(um1, (px0 - 1) & 255);
        LOADCOL(uz0, px0);
        #pragma unroll
        for (int p = 0; p < 8; ++p) {
            LOADCOL(up1, (px0 + p + 1) & 255);
            unsigned short zq[4];
            #pragma unroll
            for (int j = 0; j < 4; ++j) {
                float a = bdv[j];
                #pragma unroll
                for (int ky = 0; ky < 3; ++ky) {
                    a = fmaf(wd[ky * 3 + 0][j], um1[ky][j], a);
                    a = fmaf(wd[ky * 3 + 1][j], uz0[ky][j], a);
                    a = fmaf(wd[ky * 3 + 2][j], up1[ky][j], a);
                }
                zq[j] = f2bf(gelu_exact(a));
            }
            const int pix = sub * 8 + p;
            ushort4v zv = {zq[0], zq[1], zq[2], zq[3]};
            *(ushort4v*)&zsb2[((unsigned)(pix * 256 + c4)) ^ (((unsigned)(pix & 7)) << 3)] = zv;
            #pragma unroll
            for (int ky = 0; ky < 3; ++ky)
                #pragma unroll
                for (int j = 0; j < 4; ++j) { um1[ky][j] = uz0[ky][j]; uz0[ky][j] = up1[ky][j]; }
        }
        #undef LOADCOL
    }
    __syncthreads();

    // phase 2: z(32x256) @ W2(256x64) via mfma_f32_16x16x32_bf16.
    const int lane = t & 63, wv = t >> 6;
    const int fr = lane & 15;
    const int kb = (lane >> 4) * 8;
    const int col = wv * 16 + fr;
    f32x4v acc0 = {0.0f, 0.0f, 0.0f, 0.0f};
    f32x4v acc1 = {0.0f, 0.0f, 0.0f, 0.0f};
    #pragma unroll
    for (int kk = 0; kk < 8; ++kk) {
        const int ka = kk * 32 + kb;
        const short8v bfr = *(const short8v*)&W2T[(col * 256 + ka) ^ ((col & 7) << 3)];
        const short8v a0 = *(const short8v*)&zsb2[(fr * 256 + ka) ^ ((fr & 7) << 3)];
        const short8v a1 = *(const short8v*)&zsb2[((fr + 16) * 256 + ka) ^ ((fr & 7) << 3)];
        acc0 = __builtin_amdgcn_mfma_f32_16x16x32_bf16(a0, bfr, acc0, 0, 0, 0);
        acc1 = __builtin_amdgcn_mfma_f32_16x16x32_bf16(a1, bfr, acc1, 0, 0, 0);
    }
    const float c2v = c2[col];
    #pragma unroll
    for (int r = 0; r < 4; ++r) {
        const int prow = (lane >> 4) * 4 + r;
        const size_t tok0g = (size_t)b * HWq + ((size_t)hh << 8) + ww0;
        out[(tok0g + prow) * 64 + col] += acc0[r] + c2v;
        out[(tok0g + 16 + prow) * 64 + col] += acc1[r] + c2v;
    }
}

extern "C" void kernel_launch(void* const* d_in, const int* in_sizes, int n_in,
                              void* d_out, int out_size, void* d_ws, size_t ws_size,
                              hipStream_t stream) {
    const float* x    = (const float*)d_in[0];
    const float* ref  = (const float*)d_in[1];
    const float* g1   = (const float*)d_in[2];
    const float* be1  = (const float*)d_in[3];
    const float* g2   = (const float*)d_in[4];
    const float* be2  = (const float*)d_in[5];
    const float* Woff = (const float*)d_in[6];
    const float* boff = (const float*)d_in[7];
    const float* Wa   = (const float*)d_in[8];
    const float* ba   = (const float*)d_in[9];
    const float* Wv   = (const float*)d_in[10];
    const float* bv   = (const float*)d_in[11];
    const float* Wo   = (const float*)d_in[12];
    const float* bo   = (const float*)d_in[13];
    const float* W1   = (const float*)d_in[14];
    const float* c1   = (const float*)d_in[15];
    const float* Wdw  = (const float*)d_in[16];
    const float* bdw  = (const float*)d_in[17];
    const float* W2   = (const float*)d_in[18];
    const float* c2   = (const float*)d_in[19];

    float* out = (float*)d_out;
    float* ws = (float*)d_ws;
    unsigned short* v16 = (unsigned short*)ws;                         // B*2*HW*32 bf16 = 2,097,152 floats
    float* loc_ws  = ws + (size_t)Bq * 2 * HWq * 16;                   // NTOK*36 floats
    float* attn_ws = loc_ws + (size_t)NTOK * 36;                       // NTOK*18 floats
    unsigned short* y_ws = (unsigned short*)(attn_ws + (size_t)NTOK * 18); // NTOK*256 bf16

    hipLaunchKernelGGL(kA, dim3(NTOK / TOKA), dim3(512), 0, stream,
                       x, ref, g1, be1, Woff, boff, Wa, ba, Wv, bv,
                       v16, loc_ws, attn_ws);
    hipLaunchKernelGGL(kB, dim3(NTOK / TOKB), dim3(256), 0, stream,
                       x, v16, loc_ws, attn_ws, Wo, bo, out);
    hipLaunchKernelGGL(kC, dim3(NTOK / TOKC), dim3(512), 0, stream,
                       out, g2, be2, W1, c1, y_ws);
    hipLaunchKernelGGL(kD, dim3(Bq * Hq * (Wq / PIXD)), dim3(256), 0, stream,
                       y_ws, Wdw, bdw, W2, c2, out);
}

// Round 8
// 149.584 us; speedup vs baseline: 3.7092x; 1.0301x over previous
//
#include <hip/hip_runtime.h>
#include <math.h>

#define Bq 2
#define Hq 128
#define Wq 256
#define Cq 64
#define HIDq 256
#define HWq (Hq * Wq)
#define NTOK (Bq * HWq)

#define TOKA 128
#define TOKB 32
#define TOKC 64
#define PIXD 32

typedef __attribute__((ext_vector_type(8))) short short8v;
typedef __attribute__((ext_vector_type(4))) float f32x4v;
typedef __attribute__((ext_vector_type(4))) unsigned short ushort4v;

__device__ inline float gelu_exact(float x) {
    return 0.5f * x * (1.0f + erff(x * 0.70710678118654752440f));
}

__device__ inline unsigned short f2bf(float f) {
    unsigned int u = __float_as_uint(f);
    u += 0x7FFFu + ((u >> 16) & 1u);
    return (unsigned short)(u >> 16);
}

__device__ inline float bf2f(unsigned short u) {
    return __uint_as_float(((unsigned int)u) << 16);
}

// ============ Kernel A: LN1 + fused {Wv | Woff | Wa} GEMM, softmax, loc ======
// 512 threads, 128 tokens/block. Flat LDS: Wc[64][120] | hsb[128][68] | logit[128][20]
__global__ __launch_bounds__(512, 4) void kA(
    const float* __restrict__ x, const float* __restrict__ ref,
    const float* __restrict__ g1, const float* __restrict__ be1,
    const float* __restrict__ Woff, const float* __restrict__ boff,
    const float* __restrict__ Wa, const float* __restrict__ ba,
    const float* __restrict__ Wv, const float* __restrict__ bv,
    unsigned short* __restrict__ v16, float* __restrict__ loc_ws, float* __restrict__ attn_ws)
{
    __shared__ float lds[64 * 120 + TOKA * 68 + TOKA * 20];
#define WcF(j, c)   lds[(j) * 120 + (c)]
#define HSB(tk, ch) lds[7680 + (tk) * 68 + (ch)]
#define LG(tk, kk)  lds[7680 + TOKA * 68 + (tk) * 20 + (kk)]
    const int t = threadIdx.x;
    const int tok0 = blockIdx.x * TOKA;
    const int b = tok0 >> 15;          // HW = 32768
    const int pix0 = tok0 & (HWq - 1);

    // ---- stage fused weight matrix (cols: 0..63 Wv, 64..99 Woff, 100..117 Wa)
    for (int idx = t; idx < 64 * 120; idx += 512) {
        const int j = idx / 120, c = idx - j * 120;
        float w = 0.0f;
        if (c < 64) w = Wv[j * 64 + c];
        else if (c < 100) w = Woff[j * 36 + (c - 64)];
        else if (c < 118) w = Wa[j * 18 + (c - 100)];
        WcF(j, c) = w;
    }

    // ---- LayerNorm: thread = (token, quarter). Coalesced loads, 2-step shuffle.
    {
        const int tok = t >> 2, part = t & 3;
        const int chb = part * 16;
        const float* xp = x + (size_t)(tok0 + tok) * 64 + chb;
        const float4 v0 = ((const float4*)xp)[0];
        const float4 v1 = ((const float4*)xp)[1];
        const float4 v2 = ((const float4*)xp)[2];
        const float4 v3 = ((const float4*)xp)[3];
        float s = ((v0.x + v0.y) + (v0.z + v0.w)) + ((v1.x + v1.y) + (v1.z + v1.w))
                + ((v2.x + v2.y) + (v2.z + v2.w)) + ((v3.x + v3.y) + (v3.z + v3.w));
        float s2 = 0.0f;
        s2 = fmaf(v0.x, v0.x, s2); s2 = fmaf(v0.y, v0.y, s2);
        s2 = fmaf(v0.z, v0.z, s2); s2 = fmaf(v0.w, v0.w, s2);
        s2 = fmaf(v1.x, v1.x, s2); s2 = fmaf(v1.y, v1.y, s2);
        s2 = fmaf(v1.z, v1.z, s2); s2 = fmaf(v1.w, v1.w, s2);
        s2 = fmaf(v2.x, v2.x, s2); s2 = fmaf(v2.y, v2.y, s2);
        s2 = fmaf(v2.z, v2.z, s2); s2 = fmaf(v2.w, v2.w, s2);
        s2 = fmaf(v3.x, v3.x, s2); s2 = fmaf(v3.y, v3.y, s2);
        s2 = fmaf(v3.z, v3.z, s2); s2 = fmaf(v3.w, v3.w, s2);
        s  += __shfl_xor(s, 1);  s2 += __shfl_xor(s2, 1);
        s  += __shfl_xor(s, 2);  s2 += __shfl_xor(s2, 2);
        const float m  = s * (1.0f / 64.0f);
        const float var = fmaf(-m, m, s2 * (1.0f / 64.0f));
        const float rs = rsqrtf(var + 1e-5f);
        const float nb = -m * rs;
        const float4 gA = *(const float4*)(g1 + chb),     gB = *(const float4*)(g1 + chb + 4);
        const float4 gC = *(const float4*)(g1 + chb + 8), gD = *(const float4*)(g1 + chb + 12);
        const float4 bA = *(const float4*)(be1 + chb),     bB = *(const float4*)(be1 + chb + 4);
        const float4 bC = *(const float4*)(be1 + chb + 8), bD = *(const float4*)(be1 + chb + 12);
        float4* hrow = (float4*)&HSB(tok, chb);
        float4 h0 = {fmaf(fmaf(v0.x, rs, nb), gA.x, bA.x), fmaf(fmaf(v0.y, rs, nb), gA.y, bA.y),
                     fmaf(fmaf(v0.z, rs, nb), gA.z, bA.z), fmaf(fmaf(v0.w, rs, nb), gA.w, bA.w)};
        float4 h1 = {fmaf(fmaf(v1.x, rs, nb), gB.x, bB.x), fmaf(fmaf(v1.y, rs, nb), gB.y, bB.y),
                     fmaf(fmaf(v1.z, rs, nb), gB.z, bB.z), fmaf(fmaf(v1.w, rs, nb), gB.w, bB.w)};
        float4 h2 = {fmaf(fmaf(v2.x, rs, nb), gC.x, bC.x), fmaf(fmaf(v2.y, rs, nb), gC.y, bC.y),
                     fmaf(fmaf(v2.z, rs, nb), gC.z, bC.z), fmaf(fmaf(v2.w, rs, nb), gC.w, bC.w)};
        float4 h3 = {fmaf(fmaf(v3.x, rs, nb), gD.x, bD.x), fmaf(fmaf(v3.y, rs, nb), gD.y, bD.y),
                     fmaf(fmaf(v3.z, rs, nb), gD.z, bD.z), fmaf(fmaf(v3.w, rs, nb), gD.w, bD.w)};
        hrow[0] = h0; hrow[1] = h1; hrow[2] = h2; hrow[3] = h3;
    }
    __syncthreads();

    // ---- GEMM: 32 token-groups x 16 col-groups; lane owns cols {cg*4..+3, 64+cg*4..+3}
    const int cg = t & 15, tg = t >> 4;
    const int tb = tg * 4;
    const int c0 = cg * 4;
    float acc[4][8];
    #pragma unroll
    for (int i = 0; i < 4; ++i)
        #pragma unroll
        for (int q = 0; q < 8; ++q) acc[i][q] = 0.0f;

    for (int j = 0; j < 64; j += 4) {
        const float4 h0 = *(const float4*)&HSB(tb + 0, j);
        const float4 h1 = *(const float4*)&HSB(tb + 1, j);
        const float4 h2 = *(const float4*)&HSB(tb + 2, j);
        const float4 h3 = *(const float4*)&HSB(tb + 3, j);
        const float hv[4][4] = {{h0.x,h0.y,h0.z,h0.w},{h1.x,h1.y,h1.z,h1.w},
                                {h2.x,h2.y,h2.z,h2.w},{h3.x,h3.y,h3.z,h3.w}};
        #pragma unroll
        for (int jj = 0; jj < 4; ++jj) {
            const float4 wA = *(const float4*)&WcF(j + jj, c0);
            const float4 wB = *(const float4*)&WcF(j + jj, 64 + c0);
            const float wv8[8] = {wA.x,wA.y,wA.z,wA.w,wB.x,wB.y,wB.z,wB.w};
            #pragma unroll
            for (int i = 0; i < 4; ++i)
                #pragma unroll
                for (int q = 0; q < 8; ++q)
                    acc[i][q] = fmaf(hv[i][jj], wv8[q], acc[i][q]);
        }
    }

    // ---- epilogue: v -> global bf16 (ushort4/token), off -> loc direct, attn -> LDS
    {
        const int n = c0 >> 5, cc = c0 & 31;
        const float4 bv4 = *(const float4*)&bv[c0];
        #pragma unroll
        for (int i = 0; i < 4; ++i) {
            const int pix = pix0 + tb + i;
            ushort4v o = {f2bf(acc[i][0] + bv4.x), f2bf(acc[i][1] + bv4.y),
                          f2bf(acc[i][2] + bv4.z), f2bf(acc[i][3] + bv4.w)};
            *(ushort4v*)&v16[((size_t)(b * 2 + n) * HWq + pix) * 32 + cc] = o;
        }
    }
    if (cg <= 8) {                        // off cols 64..99 -> loc = ref + off + boff
        const int co0 = c0;               // 0..32
        #pragma unroll
        for (int i = 0; i < 4; ++i) {
            const size_t tokg = (size_t)tok0 + tb + i;
            #pragma unroll
            for (int q = 0; q < 4; ++q) {
                const int co = co0 + q;
                const int rco = (co >= 18) ? co - 18 : co;
                loc_ws[tokg * 36 + co] = ref[tokg * 18 + rco] + acc[i][4 + q] + boff[co];
            }
        }
    } else if (cg <= 13) {                // attn logit cols 100..117
        #pragma unroll
        for (int q = 0; q < 4; ++q) {
            const int c = 64 + c0 + q;
            if (c < 118) {
                const float bav = ba[c - 100];
                #pragma unroll
                for (int i = 0; i < 4; ++i) LG(tb + i, c - 100) = acc[i][4 + q] + bav;
            }
        }
    }
    __syncthreads();

    // ---- softmax per (token, head)
    if (t < TOKA * 2) {
        const int tk = t >> 1, head = t & 1;
        float mx = -1e30f;
        #pragma unroll
        for (int k = 0; k < 9; ++k) mx = fmaxf(mx, LG(tk, head * 9 + k));
        float e[9], s = 0.0f;
        #pragma unroll
        for (int k = 0; k < 9; ++k) { e[k] = expf(LG(tk, head * 9 + k) - mx); s += e[k]; }
        const float inv = 1.0f / s;
        float* dst = &attn_ws[(size_t)(tok0 + tk) * 18 + head * 9];
        #pragma unroll
        for (int k = 0; k < 9; ++k) dst[k] = e[k] * inv;
    }
#undef WcF
#undef HSB
#undef LG
}

// ============ Kernel B: corner-parallel bilinear sample + Wo + residual ======
// 512 threads. Gather layout: lane = corner(2b) | head(1b) | chan-quad(3b).
__global__ __launch_bounds__(512) void kB(
    const float* __restrict__ x, const unsigned short* __restrict__ v16,
    const float* __restrict__ loc_ws, const float* __restrict__ attn_ws,
    const float* __restrict__ Wo, const float* __restrict__ bo,
    float* __restrict__ out)
{
    __shared__ float wt4[TOKB * 18][4];
    __shared__ int   px4[TOKB * 18][4];
    __shared__ float sout[TOKB][68];
    const int t = threadIdx.x;
    // XCD-chunked swizzle: 2048 blocks, 8 XCDs, 256 contiguous per XCD
    const int bid = (blockIdx.x & 7) * (NTOK / TOKB / 8) + (blockIdx.x >> 3);
    const int tok0 = bid * TOKB;
    const int b = tok0 >> 15;

    // ---- phase A: one lane per (token, head, k): weights+indices, attn folded
    for (int idx = t; idx < TOKB * 18; idx += 512) {
        const int tk = idx / 18, rem = idx - tk * 18;   // rem = head*9 + k
        const size_t tokg = (size_t)tok0 + tk;
        const float gx = loc_ws[tokg * 36 + rem * 2];
        const float gy = loc_ws[tokg * 36 + rem * 2 + 1];
        const float a  = attn_ws[tokg * 18 + rem];
        const float ix = fmaf(gx, 128.0f, 127.5f);
        const float iy = fmaf(gy, 64.0f, 63.5f);
        const float x0f = floorf(ix), y0f = floorf(iy);
        const float wx1 = ix - x0f, wy1 = iy - y0f;
        const float wx0 = 1.0f - wx1, wy0 = 1.0f - wy1;
        const int x0 = (int)x0f, y0 = (int)y0f;
        const int x1i = x0 + 1, y1i = y0 + 1;
        const int x0c = min(max(x0, 0), Wq - 1), y0c = min(max(y0, 0), Hq - 1);
        const int x1c = min(max(x1i, 0), Wq - 1), y1c = min(max(y1i, 0), Hq - 1);
        const bool vx0 = (x0 >= 0) & (x0 <= Wq - 1);
        const bool vy0 = (y0 >= 0) & (y0 <= Hq - 1);
        const bool vx1 = (x1i >= 0) & (x1i <= Wq - 1);
        const bool vy1 = (y1i >= 0) & (y1i <= Hq - 1);
        const float ax0 = a * wx0, ax1 = a * wx1;
        float4 w = {(vx0 && vy0) ? ax0 * wy0 : 0.0f,
                    (vx1 && vy0) ? ax1 * wy0 : 0.0f,
                    (vx0 && vy1) ? ax0 * wy1 : 0.0f,
                    (vx1 && vy1) ? ax1 * wy1 : 0.0f};
        int4 p = {(((y0c << 8) + x0c) << 5), (((y0c << 8) + x1c) << 5),
                  (((y1c << 8) + x0c) << 5), (((y1c << 8) + x1c) << 5)};
        *(float4*)wt4[idx] = w;
        *(int4*)px4[idx] = p;
    }
    __syncthreads();

    // ---- phase B: corner-parallel gathers. wave handles 4 tokens.
    const int lane = t & 63, wvid = t >> 6;          // 8 waves
    const int c = lane >> 4;                         // corner 0..3
    const int n = (lane >> 3) & 1;                   // head
    const int l = lane & 7;                          // channel quad
    const unsigned short* __restrict__ vimg = v16 + (size_t)(b * 2 + n) * HWq * 32;
    for (int i = 0; i < 4; ++i) {
        const int tk = wvid * 4 + i;
        const int base = tk * 18 + n * 9;
        float a0 = 0.0f, a1 = 0.0f, a2 = 0.0f, a3 = 0.0f;
        #pragma unroll
        for (int k = 0; k < 9; ++k) {
            const float w = wt4[base + k][c];
            const int   p = px4[base + k][c];
            const ushort4v v4 = *(const ushort4v*)&vimg[p + l * 4];
            a0 = fmaf(w, bf2f(v4[0]), a0);
            a1 = fmaf(w, bf2f(v4[1]), a1);
            a2 = fmaf(w, bf2f(v4[2]), a2);
            a3 = fmaf(w, bf2f(v4[3]), a3);
        }
        // reduce 4 corners (lane bits 4,5)
        a0 += __shfl_xor(a0, 16); a1 += __shfl_xor(a1, 16);
        a2 += __shfl_xor(a2, 16); a3 += __shfl_xor(a3, 16);
        a0 += __shfl_xor(a0, 32); a1 += __shfl_xor(a1, 32);
        a2 += __shfl_xor(a2, 32); a3 += __shfl_xor(a3, 32);
        if (lane < 16) {        // lane = n*8+l -> channels n*32 + l*4 ..+3
            float4 o = {a0, a1, a2, a3};
            *(float4*)&sout[tk][lane * 4] = o;
        }
    }
    __syncthreads();

    // ---- Wo GEMM: thread -> (tok = t>>4, cols (t&15)*4), Wo via L1
    const int cg = t & 15, tg = t >> 4;              // tg 0..31
    const int cb = cg * 4;
    float acc4[4] = {0.0f, 0.0f, 0.0f, 0.0f};
    for (int j = 0; j < 64; j += 4) {
        const float4 h = *(const float4*)&sout[tg][j];
        const float hv[4] = {h.x, h.y, h.z, h.w};
        #pragma unroll
        for (int jj = 0; jj < 4; ++jj) {
            const float4 w = *(const float4*)&Wo[(size_t)(j + jj) * 64 + cb];
            acc4[0] = fmaf(hv[jj], w.x, acc4[0]);
            acc4[1] = fmaf(hv[jj], w.y, acc4[1]);
            acc4[2] = fmaf(hv[jj], w.z, acc4[2]);
            acc4[3] = fmaf(hv[jj], w.w, acc4[3]);
        }
    }
    const float4 bo4 = *(const float4*)&bo[cb];
    const size_t tokg = (size_t)tok0 + tg;
    const float4 r = *(const float4*)&x[tokg * 64 + cb];
    float4 o = {acc4[0]+bo4.x+r.x, acc4[1]+bo4.y+r.y, acc4[2]+bo4.z+r.z, acc4[3]+bo4.w+r.w};
    *(float4*)&out[tokg * 64 + cb] = o;
}

// ============ Kernel C: LN2 + bf16 MFMA W1 + GELU -> y (bf16) ================
// 512 threads (8 waves), 64 tokens/block.
__global__ __launch_bounds__(512) void kC(
    const float* __restrict__ x1, const float* __restrict__ g2, const float* __restrict__ be2,
    const float* __restrict__ W1, const float* __restrict__ c1,
    unsigned short* __restrict__ y_ws)
{
    __shared__ unsigned short W1T[256 * 64];    // bf16 [col][k], swizzled (32 KB)
    __shared__ unsigned short hb2[TOKC * 64];   // bf16 [tok][k], swizzled (8 KB)
    __shared__ unsigned short ytile[TOKC * 256];// bf16 [tok][col], swizzled (32 KB)
    const int t = threadIdx.x;
    const int tok0 = blockIdx.x * TOKC;

    // ---- stage W1 -> bf16 transposed swizzled
    #pragma unroll 4
    for (int i = 0; i < 16; ++i) {
        const int p = t + i * 512;              // p < 8192
        const int c = p & 255, k2 = p >> 8;     // k = 2*k2
        const float w0 = W1[(size_t)(2 * k2) * 256 + c];
        const float w1 = W1[(size_t)(2 * k2 + 1) * 256 + c];
        const unsigned int pk = (unsigned int)f2bf(w0) | ((unsigned int)f2bf(w1) << 16);
        const unsigned int uidx = ((unsigned int)(c * 32 + k2)) ^ (((unsigned int)(c & 7)) << 2);
        ((unsigned int*)W1T)[uidx] = pk;
    }

    // ---- LN2: thread = (token, quarter), 2-step shuffle; write h as bf16
    if (t < TOKC * 4) {
        const int tok = t >> 2, part = t & 3;
        const int chb = part * 16;
        const float* xp = x1 + (size_t)(tok0 + tok) * 64 + chb;
        const float4 v0 = ((const float4*)xp)[0];
        const float4 v1 = ((const float4*)xp)[1];
        const float4 v2 = ((const float4*)xp)[2];
        const float4 v3 = ((const float4*)xp)[3];
        float s = ((v0.x + v0.y) + (v0.z + v0.w)) + ((v1.x + v1.y) + (v1.z + v1.w))
                + ((v2.x + v2.y) + (v2.z + v2.w)) + ((v3.x + v3.y) + (v3.z + v3.w));
        float s2 = 0.0f;
        s2 = fmaf(v0.x, v0.x, s2); s2 = fmaf(v0.y, v0.y, s2);
        s2 = fmaf(v0.z, v0.z, s2); s2 = fmaf(v0.w, v0.w, s2);
        s2 = fmaf(v1.x, v1.x, s2); s2 = fmaf(v1.y, v1.y, s2);
        s2 = fmaf(v1.z, v1.z, s2); s2 = fmaf(v1.w, v1.w, s2);
        s2 = fmaf(v2.x, v2.x, s2); s2 = fmaf(v2.y, v2.y, s2);
        s2 = fmaf(v2.z, v2.z, s2); s2 = fmaf(v2.w, v2.w, s2);
        s2 = fmaf(v3.x, v3.x, s2); s2 = fmaf(v3.y, v3.y, s2);
        s2 = fmaf(v3.z, v3.z, s2); s2 = fmaf(v3.w, v3.w, s2);
        s  += __shfl_xor(s, 1);  s2 += __shfl_xor(s2, 1);
        s  += __shfl_xor(s, 2);  s2 += __shfl_xor(s2, 2);
        const float m  = s * (1.0f / 64.0f);
        const float var = fmaf(-m, m, s2 * (1.0f / 64.0f));
        const float rs = rsqrtf(var + 1e-5f);
        const float nb = -m * rs;
        const float vv[16] = {v0.x,v0.y,v0.z,v0.w, v1.x,v1.y,v1.z,v1.w,
                              v2.x,v2.y,v2.z,v2.w, v3.x,v3.y,v3.z,v3.w};
        unsigned int pk[8];
        #pragma unroll
        for (int q = 0; q < 8; ++q) {
            const float hA = fmaf(fmaf(vv[2*q], rs, nb), g2[chb + 2*q], be2[chb + 2*q]);
            const float hB = fmaf(fmaf(vv[2*q+1], rs, nb), g2[chb + 2*q+1], be2[chb + 2*q+1]);
            pk[q] = (unsigned int)f2bf(hA) | ((unsigned int)f2bf(hB) << 16);
        }
        const unsigned int swz = ((unsigned int)(tok & 7)) << 3;
        unsigned int hi0 = ((unsigned int)(tok * 64 + chb)) ^ swz;
        unsigned int hi1 = ((unsigned int)(tok * 64 + chb + 8)) ^ swz;
        uint4 gA = {pk[0], pk[1], pk[2], pk[3]};
        uint4 gB = {pk[4], pk[5], pk[6], pk[7]};
        *(uint4*)&hb2[hi0] = gA;
        *(uint4*)&hb2[hi1] = gB;
    }
    __syncthreads();

    // ---- MFMA: wave w: M-tile (w&3), N-quad (w>>2). 16 mfma/wave.
    const int lane = t & 63, wv = t >> 6;
    const int mtile = wv & 3, nquad = wv >> 2;
    const int fr = lane & 15, kb = (lane >> 4) * 8;
    const int atok = mtile * 16 + fr;
    f32x4v acc[8];
    #pragma unroll
    for (int nt = 0; nt < 8; ++nt) acc[nt] = (f32x4v){0.0f, 0.0f, 0.0f, 0.0f};

    #pragma unroll
    for (int ks = 0; ks < 2; ++ks) {
        const short8v a = *(const short8v*)&hb2[(atok * 64 + ks * 32 + kb) ^ ((atok & 7) << 3)];
        #pragma unroll
        for (int nt = 0; nt < 8; ++nt) {
            const int col = nquad * 128 + nt * 16 + fr;
            const short8v bfr = *(const short8v*)&W1T[(col * 64 + ks * 32 + kb) ^ ((col & 7) << 3)];
            acc[nt] = __builtin_amdgcn_mfma_f32_16x16x32_bf16(a, bfr, acc[nt], 0, 0, 0);
        }
    }

    // ---- bias + GELU -> ytile (bf16, swizzled)
    #pragma unroll
    for (int nt = 0; nt < 8; ++nt) {
        const int col = nquad * 128 + nt * 16 + fr;
        const float c1v = c1[col];
        #pragma unroll
        for (int r = 0; r < 4; ++r) {
            const int tok = mtile * 16 + (lane >> 4) * 4 + r;
            const float val = gelu_exact(acc[nt][r] + c1v);
            ytile[((unsigned)(tok * 256 + col)) ^ (((unsigned)(tok & 7)) << 3)] = f2bf(val);
        }
    }
    __syncthreads();

    // ---- coalesced y write: thread t -> row t>>3, 32 ushorts
    {
        const int row = t >> 3, cb = (t & 7) * 32;
        const unsigned int swz = ((unsigned int)(row & 7)) << 3;
        unsigned short* dst = y_ws + (size_t)(tok0 + row) * 256 + cb;
        #pragma unroll
        for (int j = 0; j < 4; ++j) {
            const unsigned int hidx = ((unsigned int)(row * 256 + cb + j * 8)) ^ swz;
            *(uint4*)(dst + j * 8) = *(const uint4*)&ytile[hidx];
        }
    }
}

// ============ Kernel D: depthwise 3x3 (vectorized) + GELU + MFMA W2 ==========
// 256 threads: lane = channel-quad (4 ch), t>>6 = pixel sub-strip of 8.
__global__ __launch_bounds__(256) void kD(
    const unsigned short* __restrict__ y_ws, const float* __restrict__ Wdw, const float* __restrict__ bdw,
    const float* __restrict__ W2, const float* __restrict__ c2,
    float* __restrict__ out)
{
    __shared__ unsigned short W2T[64 * 256];    // bf16 [col][k], swizzled (32 KB)
    __shared__ unsigned short zsb2[PIXD * 256]; // bf16 [pix][k], swizzled (16 KB)
    const int t = threadIdx.x;
    // XCD-chunked swizzle: 2048 blocks, 256 contiguous per XCD (row locality in L2)
    const int bid = (blockIdx.x & 7) * 256 + (blockIdx.x >> 3);
    const int b = bid >> 10;                    // 1024 per batch
    const int rem = bid & 1023;
    const int hh = rem >> 3;                    // 8 strips per row
    const int ww0 = (rem & 7) * PIXD;

    // stage W2 -> bf16, transposed, swizzled
    #pragma unroll 4
    for (int i = 0; i < 32; ++i) {
        const int p = t + i * 256;             // p < 8192
        const int c = p & 63, k2 = p >> 6;     // k = 2*k2
        const float w0 = W2[(size_t)(2 * k2) * 64 + c];
        const float w1 = W2[(size_t)(2 * k2 + 1) * 64 + c];
        const unsigned int pk = (unsigned int)f2bf(w0) | ((unsigned int)f2bf(w1) << 16);
        const unsigned int uidx = ((unsigned int)(c * 128 + k2)) ^ (((unsigned int)(c & 7)) << 2);
        ((unsigned int*)W2T)[uidx] = pk;
    }

    // phase 1: depthwise conv. Thread = 4 channels x 8-pixel sub-strip.
    {
        const int lane = t & 63, sub = t >> 6;
        const int c4 = lane * 4;
        const int px0 = ww0 + sub * 8;
        const unsigned short* __restrict__ yb = y_ws + (size_t)b * HWq * 256;
        const bool r0ok = (hh > 0), r2ok = (hh < Hq - 1);
        const int y0r = (hh - 1) << 8, y1r = hh << 8, y2r = (hh + 1) << 8;

        float um1[3][4], uz0[3][4], up1[3][4];
        #define LOADCOL(dst, xx) do {                                              \
            ushort4v v0q = r0ok ? *(const ushort4v*)&yb[((size_t)(y0r + (xx)) << 8) + c4] : (ushort4v){0,0,0,0}; \
            ushort4v v1q =        *(const ushort4v*)&yb[((size_t)(y1r + (xx)) << 8) + c4]; \
            ushort4v v2q = r2ok ? *(const ushort4v*)&yb[((size_t)(y2r + (xx)) << 8) + c4] : (ushort4v){0,0,0,0}; \
            _Pragma("unroll")                                                      \
            for (int j = 0; j < 4; ++j) {                                          \
                dst[0][j] = bf2f(v0q[j]); dst[1][j] = bf2f(v1q[j]); dst[2][j] = bf2f(v2q[j]); \
            } } while (0)

        float wd[9][4], bdv[4];
        #pragma unroll
        for (int j = 0; j < 4; ++j) {
            bdv[j] = bdw[c4 + j];
            #pragma unroll
            for (int q = 0; q < 9; ++q) wd[q][j] = Wdw[(c4 + j) * 9 + q];
        }

        LOADCOL(um1, (px0 - 1) & 255);
        LOADCOL(uz0, px0);
        #pragma unroll
        for (int p = 0; p < 8; ++p) {
            LOADCOL(up1, (px0 + p + 1) & 255);
            unsigned short zq[4];
            #pragma unroll
            for (int j = 0; j < 4; ++j) {
                float a = bdv[j];
                #pragma unroll
                for (int ky = 0; ky < 3; ++ky) {
                    a = fmaf(wd[ky * 3 + 0][j], um1[ky][j], a);
                    a = fmaf(wd[ky * 3 + 1][j], uz0[ky][j], a);
                    a = fmaf(wd[ky * 3 + 2][j], up1[ky][j], a);
                }
                zq[j] = f2bf(gelu_exact(a));
            }
            const int pix = sub * 8 + p;
            ushort4v zv = {zq[0], zq[1], zq[2], zq[3]};
            *(ushort4v*)&zsb2[((unsigned)(pix * 256 + c4)) ^ (((unsigned)(pix & 7)) << 3)] = zv;
            #pragma unroll
            for (int ky = 0; ky < 3; ++ky)
                #pragma unroll
                for (int j = 0; j < 4; ++j) { um1[ky][j] = uz0[ky][j]; uz0[ky][j] = up1[ky][j]; }
        }
        #undef LOADCOL
    }
    __syncthreads();

    // phase 2: z(32x256) @ W2(256x64) via mfma_f32_16x16x32_bf16.
    const int lane = t & 63, wv = t >> 6;
    const int fr = lane & 15;
    const int kb = (lane >> 4) * 8;
    const int col = wv * 16 + fr;
    f32x4v acc0 = {0.0f, 0.0f, 0.0f, 0.0f};
    f32x4v acc1 = {0.0f, 0.0f, 0.0f, 0.0f};
    #pragma unroll
    for (int kk = 0; kk < 8; ++kk) {
        const int ka = kk * 32 + kb;
        const short8v bfr = *(const short8v*)&W2T[(col * 256 + ka) ^ ((col & 7) << 3)];
        const short8v a0 = *(const short8v*)&zsb2[(fr * 256 + ka) ^ ((fr & 7) << 3)];
        const short8v a1 = *(const short8v*)&zsb2[((fr + 16) * 256 + ka) ^ ((fr & 7) << 3)];
        acc0 = __builtin_amdgcn_mfma_f32_16x16x32_bf16(a0, bfr, acc0, 0, 0, 0);
        acc1 = __builtin_amdgcn_mfma_f32_16x16x32_bf16(a1, bfr, acc1, 0, 0, 0);
    }
    const float c2v = c2[col];
    #pragma unroll
    for (int r = 0; r < 4; ++r) {
        const int prow = (lane >> 4) * 4 + r;
        const size_t tok0g = (size_t)b * HWq + ((size_t)hh << 8) + ww0;
        out[(tok0g + prow) * 64 + col] += acc0[r] + c2v;
        out[(tok0g + 16 + prow) * 64 + col] += acc1[r] + c2v;
    }
}

extern "C" void kernel_launch(void* const* d_in, const int* in_sizes, int n_in,
                              void* d_out, int out_size, void* d_ws, size_t ws_size,
                              hipStream_t stream) {
    const float* x    = (const float*)d_in[0];
    const float* ref  = (const float*)d_in[1];
    const float* g1   = (const float*)d_in[2];
    const float* be1  = (const float*)d_in[3];
    const float* g2   = (const float*)d_in[4];
    const float* be2  = (const float*)d_in[5];
    const float* Woff = (const float*)d_in[6];
    const float* boff = (const float*)d_in[7];
    const float* Wa   = (const float*)d_in[8];
    const float* ba   = (const float*)d_in[9];
    const float* Wv   = (const float*)d_in[10];
    const float* bv   = (const float*)d_in[11];
    const float* Wo   = (const float*)d_in[12];
    const float* bo   = (const float*)d_in[13];
    const float* W1   = (const float*)d_in[14];
    const float* c1   = (const float*)d_in[15];
    const float* Wdw  = (const float*)d_in[16];
    const float* bdw  = (const float*)d_in[17];
    const float* W2   = (const float*)d_in[18];
    const float* c2   = (const float*)d_in[19];

    float* out = (float*)d_out;
    float* ws = (float*)d_ws;
    unsigned short* v16 = (unsigned short*)ws;                         // B*2*HW*32 bf16
    float* loc_ws  = ws + (size_t)Bq * 2 * HWq * 16;                   // NTOK*36 floats
    float* attn_ws = loc_ws + (size_t)NTOK * 36;                       // NTOK*18 floats
    unsigned short* y_ws = (unsigned short*)(attn_ws + (size_t)NTOK * 18); // NTOK*256 bf16

    hipLaunchKernelGGL(kA, dim3(NTOK / TOKA), dim3(512), 0, stream,
                       x, ref, g1, be1, Woff, boff, Wa, ba, Wv, bv,
                       v16, loc_ws, attn_ws);
    hipLaunchKernelGGL(kB, dim3(NTOK / TOKB), dim3(512), 0, stream,
                       x, v16, loc_ws, attn_ws, Wo, bo, out);
    hipLaunchKernelGGL(kC, dim3(NTOK / TOKC), dim3(512), 0, stream,
                       out, g2, be2, W1, c1, y_ws);
    hipLaunchKernelGGL(kD, dim3(Bq * Hq * (Wq / PIXD)), dim3(256), 0, stream,
                       y_ws, Wdw, bdw, W2, c2, out);
}